// Round 6
// baseline (447.532 us; speedup 1.0000x reference)
//
#include <hip/hip_runtime.h>

typedef unsigned short u16;
typedef __bf16 bf16x8 __attribute__((ext_vector_type(8)));
typedef float f32x4 __attribute__((ext_vector_type(4)));
typedef u16 u16x8 __attribute__((ext_vector_type(8)));

#define B_ 16384

__device__ __forceinline__ u16 f2b(float f){
  unsigned u = __builtin_bit_cast(unsigned, f);
  u = (u + 0x7FFFu + ((u >> 16) & 1u)) >> 16;   // RNE
  return (u16)u;
}
__device__ __forceinline__ float b2f(u16 v){
  return __builtin_bit_cast(float, ((unsigned)v) << 16);
}
__device__ __forceinline__ void ld8(const u16* __restrict__ p, float* f){
  u16x8 v = *(const u16x8*)p;
  #pragma unroll
  for (int j = 0; j < 8; ++j) f[j] = b2f(v[j]);
}
__device__ __forceinline__ void st8(u16* __restrict__ p, const float* f){
  u16x8 v;
  #pragma unroll
  for (int j = 0; j < 8; ++j) v[j] = f2b(f[j]);
  *(u16x8*)p = v;
}

__device__ __forceinline__ void gload16(const u16* g, u16* lds){
  __builtin_amdgcn_global_load_lds(
      (const __attribute__((address_space(1))) unsigned int*)g,
      (__attribute__((address_space(3))) unsigned int*)lds, 16, 0, 0);
}

// ================= k_gate0: 26 gate logits per row + softmax -> G0S =========
// One wave per 16 rows; lane holds an 8-elem K-slice of all 26 weight cols.
// G0S[b][0..15] = task gates (t*4+i), [16..25] = shared gates. f32, stride 32.
__global__ __launch_bounds__(256) void k_gate0(const u16* __restrict__ xb,
    const u16* __restrict__ Wt0, const float* __restrict__ bias0,
    float* __restrict__ G0S)
{
  const int lane = threadIdx.x & 63, wave = threadIdx.x >> 6;
  const int rbase = blockIdx.x * 64 + wave * 16;
  u16x8 w[26];
  #pragma unroll
  for (int g = 0; g < 26; ++g)
    w[g] = *(const u16x8*)(Wt0 + (size_t)(2560 + g) * 512 + lane * 8);
  float bias[26];
  #pragma unroll
  for (int g = 0; g < 26; ++g) bias[g] = bias0[2560 + g];

  for (int it = 0; it < 16; ++it) {
    int row = rbase + it;
    float f[8]; ld8(xb + (size_t)row * 512 + lane * 8, f);
    float lg[26];
    #pragma unroll
    for (int g = 0; g < 26; ++g) {
      float p = 0.f;
      #pragma unroll
      for (int j = 0; j < 8; ++j) p += f[j] * b2f(w[g][j]);
      #pragma unroll
      for (int off = 1; off < 64; off <<= 1) p += __shfl_xor(p, off);
      lg[g] = p + bias[g];
    }
    float tg[16];
    #pragma unroll
    for (int t = 0; t < 4; ++t) {
      float m = fmaxf(fmaxf(lg[4*t], lg[4*t+1]), fmaxf(lg[4*t+2], lg[4*t+3]));
      float e0 = expf(lg[4*t]-m), e1 = expf(lg[4*t+1]-m);
      float e2 = expf(lg[4*t+2]-m), e3 = expf(lg[4*t+3]-m);
      float inv = 1.f / (e0+e1+e2+e3);
      tg[4*t] = e0*inv; tg[4*t+1] = e1*inv; tg[4*t+2] = e2*inv; tg[4*t+3] = e3*inv;
    }
    float sg[10];
    {
      float m = lg[16];
      #pragma unroll
      for (int j = 1; j < 10; ++j) m = fmaxf(m, lg[16+j]);
      float ssum = 0.f;
      #pragma unroll
      for (int j = 0; j < 10; ++j) { sg[j] = expf(lg[16+j]-m); ssum += sg[j]; }
      float inv = 1.f / ssum;
      #pragma unroll
      for (int j = 0; j < 10; ++j) sg[j] *= inv;
    }
    float* orow = G0S + (size_t)row * 32;
    #pragma unroll
    for (int g = 0; g < 16; ++g) if (lane == g) orow[g] = tg[g];
    #pragma unroll
    for (int j = 0; j < 10; ++j) if (lane == 16 + j) orow[16 + j] = sg[j];
  }
}

// ============ k_fused0: level-0 experts GEMM + gating mix, fused ============
// Block: 64 rows (m0) x 128 e-cols (np half of 256). Per pass p (t=0..3 then
// shared), B-tile = 256 WT0 rows = paired cols {e, e+256} of slice pair.
// BK=32, ring-3 LDS (3 x (A[64][32]+B[256][32]) = 60 KiB -> 2 blocks/CU),
// counted vmcnt(5) (depth-2 prefetch, never drain-0 in loop). 80-step runway.
// Swizzle: phys slot = (s + (r>>1)) & 3 (2-way max -> free); staging source
// slot = ((lane&3) - (lane>>3)) & 3 (chunk-independent), LDS dest linear.
__global__ __launch_bounds__(256, 2) void k_fused0(const u16* __restrict__ xb,
    const u16* __restrict__ Wt0, const float* __restrict__ bias0,
    const float* __restrict__ G0S, u16* __restrict__ T1SH)
{
  __shared__ __align__(16) u16 sm[30720];   // 3 slots x 10240 u16
  const int tid = threadIdx.x, lane = tid & 63, wave = tid >> 6;
  const int bid = blockIdx.x;                    // 512 = 8 * 64
  const int swz = (bid & 7) * 64 + (bid >> 3);
  const int m0 = (swz >> 1) * 64, np = swz & 1;

  // staging: 20 chunks of 1 KiB (A: 0..3 -> rows c*16.., B: 4..19 -> Brow (c-4)*16..)
  const int srow = lane >> 2;
  const int sig  = ((lane & 3) - (lane >> 3)) & 3;
  size_t aOff[5]; int bOff[5]; int ldst[5]; bool isA[5];
  #pragma unroll
  for (int i = 0; i < 5; ++i) {
    int c = wave * 5 + i;
    if (c < 4) {
      isA[i] = true;
      aOff[i] = (size_t)(m0 + c * 16 + srow) * 512 + sig * 8;
      bOff[i] = 0;
      ldst[i] = c * 512;
    } else {
      isA[i] = false;
      int rho = (c - 4) * 16 + srow;
      aOff[i] = 0;
      bOff[i] = (np * 128 + rho + (rho >= 128 ? 128 : 0)) * 512 + sig * 8;
      ldst[i] = 2048 + (c - 4) * 512;
    }
  }

  // ds-read offsets (u16 units)
  int aoff[4], boff[2];
  #pragma unroll
  for (int m = 0; m < 4; ++m) {
    int r = m * 16 + (lane & 15);
    aoff[m] = r * 32 + ((((lane >> 4) + (r >> 1)) & 3) * 8);
  }
  #pragma unroll
  for (int n = 0; n < 2; ++n) {
    int br = wave * 32 + n * 16 + (lane & 15);
    boff[n] = 2048 + br * 32 + ((((lane >> 4) + (br >> 1)) & 3) * 8);
  }

  f32x4 zero = {0.f,0.f,0.f,0.f};
  f32x4 acc_lo[4][2], acc_hi[4][2], shacc[4][2];
  #pragma unroll
  for (int m = 0; m < 4; ++m)
    #pragma unroll
    for (int n = 0; n < 2; ++n) { acc_lo[m][n] = zero; acc_hi[m][n] = zero; shacc[m][n] = zero; }

  #define STAGE(S, SLOT) do {                                                  \
    int js_ = ((S) & 15) * 32;                                                 \
    int ps_ = (S) >> 4;                                                        \
    int bb_ = (ps_ < 4) ? ps_ * 262144 : 1048576;                              \
    u16* sl_ = sm + (SLOT) * 10240;                                            \
    _Pragma("unroll")                                                          \
    for (int i_ = 0; i_ < 5; ++i_) {                                           \
      const u16* src_ = isA[i_] ? (xb + aOff[i_] + js_)                        \
                                : (Wt0 + bOff[i_] + bb_ + js_);                \
      gload16(src_, sl_ + ldst[i_]);                                           \
    }                                                                          \
  } while (0)

  STAGE(0, 0);
  STAGE(1, 1);
  asm volatile("s_waitcnt vmcnt(5)" ::: "memory");
  __builtin_amdgcn_s_barrier();

  const int elbase = wave * 32 + (lane & 15);
  int s = 0, cs = 0;
  for (int p = 0; p < 5; ++p) {
    for (int j = 0; j < 16; ++j, ++s) {
      if (s + 2 < 80) {
        int ns = cs + 2; ns = (ns >= 3) ? ns - 3 : ns;
        STAGE(s + 2, ns);
      }
      const u16* sa = sm + cs * 10240;
      bf16x8 av[4], bl[2], bh[2];
      #pragma unroll
      for (int m = 0; m < 4; ++m) av[m] = *(const bf16x8*)(sa + aoff[m]);
      #pragma unroll
      for (int n = 0; n < 2; ++n) {
        bl[n] = *(const bf16x8*)(sa + boff[n]);
        bh[n] = *(const bf16x8*)(sa + boff[n] + 4096);
      }
      #pragma unroll
      for (int m = 0; m < 4; ++m)
        #pragma unroll
        for (int n = 0; n < 2; ++n) {
          acc_lo[m][n] = __builtin_amdgcn_mfma_f32_16x16x32_bf16(av[m], bl[n], acc_lo[m][n], 0, 0, 0);
          acc_hi[m][n] = __builtin_amdgcn_mfma_f32_16x16x32_bf16(av[m], bh[n], acc_hi[m][n], 0, 0, 0);
        }
      if (s + 2 < 80)      asm volatile("s_waitcnt vmcnt(5)" ::: "memory");
      else if (s + 1 < 80) asm volatile("s_waitcnt vmcnt(0)" ::: "memory");
      if (s + 1 < 80) __builtin_amdgcn_s_barrier();
      cs = (cs == 2) ? 0 : cs + 1;
    }
    // ---------------- pass epilogue ----------------
    if (p < 4) {
      int bbase = p * 512 + np * 128;
      float bl0 = bias0[bbase + elbase],       bl1 = bias0[bbase + elbase + 16];
      float bh0 = bias0[bbase + 256 + elbase], bh1 = bias0[bbase + 256 + elbase + 16];
      #pragma unroll
      for (int mi = 0; mi < 4; ++mi)
        #pragma unroll
        for (int q = 0; q < 4; ++q) {
          int r = m0 + mi * 16 + ((lane >> 4) << 2) + q;
          const float* gp = G0S + (size_t)r * 32;
          float4 g  = *(const float4*)(gp + p * 4);
          float2 gsv = *(const float2*)(gp + 16 + p * 2);
          #pragma unroll
          for (int n = 0; n < 2; ++n) {
            float lo = fmaxf(acc_lo[mi][n][q] + (n ? bl1 : bl0), 0.f);
            float hi = fmaxf(acc_hi[mi][n][q] + (n ? bh1 : bh0), 0.f);
            int col = np * 128 + elbase + n * 16;
            T1SH[((size_t)p * B_ + r) * 256 + col] = f2b(g.x * lo + g.y * hi);
            shacc[mi][n][q] += gsv.x * lo + gsv.y * hi;
          }
        }
      #pragma unroll
      for (int m = 0; m < 4; ++m)
        #pragma unroll
        for (int n = 0; n < 2; ++n) { acc_lo[m][n] = zero; acc_hi[m][n] = zero; }
    } else {
      // shared pass: RMW the 4 task partials + write sh1. Drain stores first
      // (same-wave store->load to same address needs vmcnt(0); staging is done).
      asm volatile("s_waitcnt vmcnt(0)" ::: "memory");
      int bbase = 2048 + np * 128;
      float bl0 = bias0[bbase + elbase],       bl1 = bias0[bbase + elbase + 16];
      float bh0 = bias0[bbase + 256 + elbase], bh1 = bias0[bbase + 256 + elbase + 16];
      #pragma unroll
      for (int mi = 0; mi < 4; ++mi)
        #pragma unroll
        for (int q = 0; q < 4; ++q) {
          int r = m0 + mi * 16 + ((lane >> 4) << 2) + q;
          const float* gp = G0S + (size_t)r * 32;
          float4 g0 = *(const float4*)(gp + 0);
          float4 g1 = *(const float4*)(gp + 4);
          float4 g2 = *(const float4*)(gp + 8);
          float4 g3 = *(const float4*)(gp + 12);
          float gs8 = gp[24], gs9 = gp[25];
          #pragma unroll
          for (int n = 0; n < 2; ++n) {
            float shlo = fmaxf(acc_lo[mi][n][q] + (n ? bl1 : bl0), 0.f);
            float shhi = fmaxf(acc_hi[mi][n][q] + (n ? bh1 : bh0), 0.f);
            int col = np * 128 + elbase + n * 16;
            size_t i0 = ((size_t)0 * B_ + r) * 256 + col;
            size_t i1 = ((size_t)1 * B_ + r) * 256 + col;
            size_t i2 = ((size_t)2 * B_ + r) * 256 + col;
            size_t i3 = ((size_t)3 * B_ + r) * 256 + col;
            T1SH[i0] = f2b(b2f(T1SH[i0]) + g0.z * shlo + g0.w * shhi);
            T1SH[i1] = f2b(b2f(T1SH[i1]) + g1.z * shlo + g1.w * shhi);
            T1SH[i2] = f2b(b2f(T1SH[i2]) + g2.z * shlo + g2.w * shhi);
            T1SH[i3] = f2b(b2f(T1SH[i3]) + g3.z * shlo + g3.w * shhi);
            float sv = shacc[mi][n][q] + gs8 * shlo + gs9 * shhi;
            T1SH[((size_t)4 * B_ + r) * 256 + col] = f2b(sv);
          }
        }
    }
  }
  #undef STAGE
}

// ---------------- GEMM core v4 (R5, kept for gemm1/tower) ----------------
__device__ __forceinline__ void gemm_core4(const u16* __restrict__ A,
                                           const u16* __restrict__ Wt,
                                           int K, int m0, int n0, int nt,
                                           u16* sm, f32x4 acc[4][4])
{
  const int tid  = threadIdx.x;
  const int lane = tid & 63;
  const int wave = tid >> 6;
  const int wm   = ((tid >> 7) & 1) * 64;
  const int wn   = ((tid >> 6) & 1) * 64;

  f32x4 zero = {0.f, 0.f, 0.f, 0.f};
  #pragma unroll
  for (int mi = 0; mi < 4; ++mi)
    #pragma unroll
    for (int ni = 0; ni < 4; ++ni) acc[mi][ni] = zero;

  const int srow  = lane >> 3;
  const int gslot = (lane & 7) ^ srow;
  const u16* gsrc[8];
  int gdst[8];
  #pragma unroll
  for (int i = 0; i < 8; ++i) {
    int c = wave * 8 + i;
    if (c < 16) {
      gsrc[i] = A + (size_t)(m0 + c * 8 + srow) * K + gslot * 8;
      gdst[i] = c * 512;
    } else {
      gsrc[i] = Wt + (size_t)(n0 + (c - 16) * 8 + srow) * K + gslot * 8;
      gdst[i] = 8192 + (c - 16) * 512;
    }
  }

  int aoff[2][4], boff[2][4];
  #pragma unroll
  for (int kk = 0; kk < 2; ++kk) {
    #pragma unroll
    for (int m = 0; m < 4; ++m) {
      int r = wm + m * 16 + (lane & 15);
      aoff[kk][m] = r * 64 + (((kk * 4 + (lane >> 4)) ^ (r & 7)) * 8);
    }
    #pragma unroll
    for (int n = 0; n < 4; ++n) {
      int r = wn + n * 16 + (lane & 15);
      boff[kk][n] = 8192 + r * 64 + (((kk * 4 + (lane >> 4)) ^ (r & 7)) * 8);
    }
  }

  #pragma unroll
  for (int i = 0; i < 8; ++i) gload16(gsrc[i], sm + gdst[i]);
  asm volatile("s_waitcnt vmcnt(0)" ::: "memory");
  __builtin_amdgcn_s_barrier();

  for (int j = 0; j < nt; ++j) {
    if (j + 1 < nt) {
      u16* base = sm + ((j + 1) & 1) * 16384;
      #pragma unroll
      for (int i = 0; i < 8; ++i) gload16(gsrc[i] + (size_t)(j + 1) * 64, base + gdst[i]);
    }
    const u16* sa = sm + (j & 1) * 16384;
    #pragma unroll
    for (int kk = 0; kk < 2; ++kk) {
      bf16x8 av[4], bv[4];
      #pragma unroll
      for (int m = 0; m < 4; ++m) av[m] = *(const bf16x8*)(sa + aoff[kk][m]);
      #pragma unroll
      for (int n = 0; n < 4; ++n) bv[n] = *(const bf16x8*)(sa + boff[kk][n]);
      #pragma unroll
      for (int m = 0; m < 4; ++m)
        #pragma unroll
        for (int n = 0; n < 4; ++n)
          acc[m][n] = __builtin_amdgcn_mfma_f32_16x16x32_bf16(av[m], bv[n], acc[m][n], 0, 0, 0);
    }
    if (j + 1 < nt) {
      asm volatile("s_waitcnt vmcnt(0)" ::: "memory");
      __builtin_amdgcn_s_barrier();
    }
  }
}

// GEMM1: z<4: t1[z] x Wt1[z] (cols 0..511 experts, 512..515 gate logits);
//        z=4: sh1 x Wsh1 (cols 0..511).
__global__ __launch_bounds__(256) void k_gemm1(const u16* __restrict__ T1SH,
    const u16* __restrict__ Wt1, const float* __restrict__ bias1,
    u16* __restrict__ E1, float* __restrict__ G1L, u16* __restrict__ SH1E)
{
  const int z = blockIdx.z;
  const int m0 = blockIdx.x * 128, n0 = blockIdx.y * 128;
  if (z == 4 && n0 >= 512) return;
  __shared__ __align__(16) u16 sm[32768];
  f32x4 acc[4][4];
  gemm_core4(T1SH + (size_t)z * B_ * 256, Wt1 + (size_t)z * 640 * 256, 256, m0, n0, 4, sm, acc);
  const int lane = threadIdx.x & 63;
  const int wm = ((threadIdx.x >> 7) & 1) * 64, wn = ((threadIdx.x >> 6) & 1) * 64;
  const float* bias = bias1 + z * 640;
  #pragma unroll
  for (int mi = 0; mi < 4; ++mi)
    #pragma unroll
    for (int ni = 0; ni < 4; ++ni) {
      int gcol = n0 + wn + ni * 16 + (lane & 15);
      float bv = bias[gcol];
      #pragma unroll
      for (int r = 0; r < 4; ++r) {
        int grow = m0 + wm + mi * 16 + ((lane >> 4) << 2) + r;
        float v = acc[mi][ni][r] + bv;
        if (z < 4) {
          if (gcol < 512)      E1[((size_t)z * B_ + grow) * 512 + gcol] = f2b(fmaxf(v, 0.f));
          else if (gcol < 516) G1L[((size_t)z * B_ + grow) * 4 + (gcol - 512)] = v;
        } else {
          if (gcol < 512)      SH1E[(size_t)grow * 512 + gcol] = f2b(fmaxf(v, 0.f));
        }
      }
    }
}

// MIX1: 8 rows per block, vectorized
__global__ __launch_bounds__(256) void k_mix1(const u16* __restrict__ E1,
    const float* __restrict__ G1L, const u16* __restrict__ SH1E, u16* __restrict__ T2)
{
  const int b = blockIdx.x * 8 + (threadIdx.x >> 5);
  const int e0 = (threadIdx.x & 31) * 8;
  float sh0[8], sh1[8];
  ld8(SH1E + (size_t)b * 512 + e0, sh0);
  ld8(SH1E + (size_t)b * 512 + 256 + e0, sh1);
  #pragma unroll
  for (int t = 0; t < 4; ++t) {
    const float* gl = G1L + ((size_t)t * B_ + b) * 4;
    float l0 = gl[0], l1 = gl[1], l2 = gl[2], l3 = gl[3];
    float m = fmaxf(fmaxf(l0, l1), fmaxf(l2, l3));
    float x0 = expf(l0-m), x1 = expf(l1-m), x2 = expf(l2-m), x3 = expf(l3-m);
    float inv = 1.f / (x0 + x1 + x2 + x3);
    float g0 = x0*inv, g1 = x1*inv, g2 = x2*inv, g3 = x3*inv;
    float te0[8], te1[8], v[8];
    ld8(E1 + ((size_t)t * B_ + b) * 512 + e0, te0);
    ld8(E1 + ((size_t)t * B_ + b) * 512 + 256 + e0, te1);
    #pragma unroll
    for (int j = 0; j < 8; ++j)
      v[j] = g0*te0[j] + g1*te1[j] + g2*sh0[j] + g3*sh1[j];
    st8(T2 + ((size_t)t * B_ + b) * 256 + e0, v);
  }
}

// TOWER: h = relu(t2[z] x Wtw[z]^T + b_tw); logits = h x w_out + b_out; softmax2; clip.
__global__ __launch_bounds__(256) void k_tower(const u16* __restrict__ T2,
    const u16* __restrict__ Wtw, const float* __restrict__ b_tw,
    const float* __restrict__ w_out, const float* __restrict__ b_out,
    float* __restrict__ out)
{
  __shared__ __align__(16) u16 sm[32768];
  __shared__ float part[2][128][2];
  f32x4 acc[4][4];
  const int z = blockIdx.z;
  const int m0 = blockIdx.x * 128;
  gemm_core4(T2 + (size_t)z * B_ * 256, Wtw + (size_t)z * 128 * 256, 256, m0, 0, 4, sm, acc);
  const int lane = threadIdx.x & 63;
  const int wm = ((threadIdx.x >> 7) & 1) * 64, wn = ((threadIdx.x >> 6) & 1) * 64;
  #pragma unroll
  for (int mi = 0; mi < 4; ++mi) {
    #pragma unroll
    for (int r = 0; r < 4; ++r) {
      float p0 = 0.f, p1 = 0.f;
      #pragma unroll
      for (int ni = 0; ni < 4; ++ni) {
        int col = wn + ni * 16 + (lane & 15);
        float h = fmaxf(acc[mi][ni][r] + b_tw[z * 128 + col], 0.f);
        p0 += h * w_out[(z * 128 + col) * 2 + 0];
        p1 += h * w_out[(z * 128 + col) * 2 + 1];
      }
      #pragma unroll
      for (int off = 1; off < 16; off <<= 1) {
        p0 += __shfl_xor(p0, off);
        p1 += __shfl_xor(p1, off);
      }
      if ((lane & 15) == 0) {
        int rowl = wm + mi * 16 + ((lane >> 4) << 2) + r;
        part[wn >> 6][rowl][0] = p0;
        part[wn >> 6][rowl][1] = p1;
      }
    }
  }
  __syncthreads();
  if (threadIdx.x < 128) {
    int rowl = threadIdx.x;
    float l0 = part[0][rowl][0] + part[1][rowl][0] + b_out[z * 2 + 0];
    float l1 = part[0][rowl][1] + part[1][rowl][1] + b_out[z * 2 + 1];
    float mx = fmaxf(l0, l1);
    float e0 = expf(l0 - mx), e1 = expf(l1 - mx);
    float inv = 1.f / (e0 + e1);
    float p0 = fminf(fmaxf(e0 * inv, 1e-15f), 1.0f);
    float p1 = fminf(fmaxf(e1 * inv, 1e-15f), 1.0f);
    size_t o = ((size_t)z * B_ + m0 + rowl) * 2;
    out[o] = p0; out[o + 1] = p1;
  }
}

// PREP: cast x -> bf16 (8 el/thread); transposed bf16 weight panels + bias vectors.
__global__ void k_prep(const float* __restrict__ x,
    const float* __restrict__ w_task0, const float* __restrict__ b_task0,
    const float* __restrict__ w_sh0,   const float* __restrict__ b_sh0,
    const float* __restrict__ w_gate0, const float* __restrict__ b_gate0,
    const float* __restrict__ w_gsh0,  const float* __restrict__ b_gsh0,
    const float* __restrict__ w_task1, const float* __restrict__ b_task1,
    const float* __restrict__ w_sh1,   const float* __restrict__ b_sh1,
    const float* __restrict__ w_gate1, const float* __restrict__ b_gate1,
    const float* __restrict__ w_tw,
    u16* __restrict__ xb, u16* __restrict__ Wt0, float* __restrict__ bias0,
    u16* __restrict__ Wt1, float* __restrict__ bias1, u16* __restrict__ Wtw)
{
  size_t i = (size_t)blockIdx.x * 256 + threadIdx.x;
  const size_t S_X8  = (size_t)16384 * 512 / 8;
  const size_t S_WT0 = (size_t)2688 * 512;
  const size_t S_B0  = 2688;
  const size_t S_WT1 = (size_t)5 * 640 * 256;
  const size_t S_B1  = 5 * 640;
  const size_t S_WTW = (size_t)4 * 128 * 256;

  if (i < S_X8) {
    size_t o = i * 8;
    float4 a = *(const float4*)(x + o);
    float4 b = *(const float4*)(x + o + 4);
    u16x8 v;
    v[0] = f2b(a.x); v[1] = f2b(a.y); v[2] = f2b(a.z); v[3] = f2b(a.w);
    v[4] = f2b(b.x); v[5] = f2b(b.y); v[6] = f2b(b.z); v[7] = f2b(b.w);
    *(u16x8*)(xb + o) = v;
    return;
  }
  i -= S_X8;
  if (i < S_WT0) {
    int c = (int)(i / 512), f = (int)(i % 512);
    float v = 0.f;
    if (c < 2048)      { int te = c >> 8, o = c & 255; v = w_task0[((size_t)te * 512 + f) * 256 + o]; }
    else if (c < 2560) { int s = (c - 2048) >> 8, o = c & 255; v = w_sh0[((size_t)s * 512 + f) * 256 + o]; }
    else if (c < 2576) { int q = c - 2560; int t = q >> 2, gg = q & 3; v = w_gate0[((size_t)t * 512 + f) * 4 + gg]; }
    else if (c < 2586) { int j = c - 2576; v = w_gsh0[(size_t)f * 10 + j]; }
    Wt0[i] = f2b(v);
    return;
  }
  i -= S_WT0;
  if (i < S_B0) {
    int c = (int)i; float v = 0.f;
    if (c < 2048)      { int te = c >> 8, o = c & 255; v = b_task0[te * 256 + o]; }
    else if (c < 2560) { int s = (c - 2048) >> 8, o = c & 255; v = b_sh0[s * 256 + o]; }
    else if (c < 2576) { v = b_gate0[c - 2560]; }
    else if (c < 2586) { v = b_gsh0[c - 2576]; }
    bias0[c] = v;
    return;
  }
  i -= S_B0;
  if (i < S_WT1) {
    int z = (int)(i / (640 * 256)); int rem = (int)(i % (640 * 256));
    int c = rem / 256, f = rem % 256;
    float v = 0.f;
    if (z < 4) {
      if (c < 512)      { int ee = c >> 8, o = c & 255; v = w_task1[(((size_t)(z * 2 + ee)) * 256 + f) * 256 + o]; }
      else if (c < 516) { int gg = c - 512; v = w_gate1[((size_t)z * 256 + f) * 4 + gg]; }
    } else {
      if (c < 512)      { int s = c >> 8, o = c & 255; v = w_sh1[((size_t)s * 256 + f) * 256 + o]; }
    }
    Wt1[i] = f2b(v);
    return;
  }
  i -= S_WT1;
  if (i < S_B1) {
    int z = (int)(i / 640); int c = (int)(i % 640);
    float v = 0.f;
    if (z < 4) {
      if (c < 512)      { int ee = c >> 8, o = c & 255; v = b_task1[(z * 2 + ee) * 256 + o]; }
      else if (c < 516) { v = b_gate1[z * 4 + (c - 512)]; }
    } else {
      if (c < 512)      { int s = c >> 8, o = c & 255; v = b_sh1[s * 256 + o]; }
    }
    bias1[(size_t)z * 640 + c] = v;
    return;
  }
  i -= S_B1;
  if (i < S_WTW) {
    int z = (int)(i / (128 * 256)); int rem = (int)(i % (128 * 256));
    int h = rem / 256, f = rem % 256;
    Wtw[i] = f2b(w_tw[((size_t)z * 256 + f) * 128 + h]);
    return;
  }
}

extern "C" void kernel_launch(void* const* d_in, const int* in_sizes, int n_in,
                              void* d_out, int out_size, void* d_ws, size_t ws_size,
                              hipStream_t stream)
{
  (void)in_sizes; (void)n_in; (void)out_size; (void)ws_size;
  const float* x       = (const float*)d_in[0];
  const float* w_task0 = (const float*)d_in[1];
  const float* b_task0 = (const float*)d_in[2];
  const float* w_sh0   = (const float*)d_in[3];
  const float* b_sh0   = (const float*)d_in[4];
  const float* w_gate0 = (const float*)d_in[5];
  const float* b_gate0 = (const float*)d_in[6];
  const float* w_gsh0  = (const float*)d_in[7];
  const float* b_gsh0  = (const float*)d_in[8];
  const float* w_task1 = (const float*)d_in[9];
  const float* b_task1 = (const float*)d_in[10];
  const float* w_sh1   = (const float*)d_in[11];
  const float* b_sh1   = (const float*)d_in[12];
  const float* w_gate1 = (const float*)d_in[13];
  const float* b_gate1 = (const float*)d_in[14];
  const float* w_tw    = (const float*)d_in[15];
  const float* b_tw    = (const float*)d_in[16];
  const float* w_out   = (const float*)d_in[17];
  const float* b_out   = (const float*)d_in[18];
  float* out = (float*)d_out;

  char* ws = (char*)d_ws;
  u16*   XB    = (u16*)  (ws + 0);           //  16,777,216  [16384][512]
  u16*   WT0   = (u16*)  (ws + 16777216);    //   2,752,512  [2688][512]
  float* BIAS0 = (float*)(ws + 19529728);    //      10,752  [2688]
  u16*   WT1   = (u16*)  (ws + 19540480);    //   1,638,400  [5][640][256]
  float* BIAS1 = (float*)(ws + 21178880);    //      12,800  [5][640]
  u16*   WTW   = (u16*)  (ws + 21191680);    //     262,144  [4][128][256]
  float* G0S   = (float*)(ws + 21453824);    //   2,097,152  [16384][32] f32 gates
  u16*   T2    = (u16*)  (ws + 23550976);    //  33,554,432  [4][16384][256]
  u16*   T1SH  = (u16*)  (ws + 107043840);   //  41,943,040  [5][16384][256]
  u16*   E1    = (u16*)  (ws + 148986880);   //  67,108,864  [4][16384][512]
  float* G1L   = (float*)(ws + 216095744);   //   1,048,576  [4][16384][4]
  u16*   SH1E  = (u16*)  (ws + 217144320);   //  16,777,216  [16384][512]

  k_prep<<<13207, 256, 0, stream>>>(x, w_task0, b_task0, w_sh0, b_sh0, w_gate0, b_gate0,
      w_gsh0, b_gsh0, w_task1, b_task1, w_sh1, b_sh1, w_gate1, b_gate1, w_tw,
      XB, WT0, BIAS0, WT1, BIAS1, WTW);
  k_gate0<<<256, 256, 0, stream>>>(XB, WT0, BIAS0, G0S);
  k_fused0<<<512, 256, 0, stream>>>(XB, WT0, BIAS0, G0S, T1SH);
  k_gemm1<<<dim3(128, 5, 5), 256, 0, stream>>>(T1SH, WT1, BIAS1, E1, G1L, SH1E);
  k_mix1<<<2048, 256, 0, stream>>>(E1, G1L, SH1E, T2);
  k_tower<<<dim3(128, 1, 4), 256, 0, stream>>>(T2, WTW, b_tw, w_out, b_out, out);
}

// Round 7
// 223.107 us; speedup vs baseline: 2.0059x; 2.0059x over previous
//
#include <hip/hip_runtime.h>

typedef unsigned short u16;
typedef __bf16 bf16x8 __attribute__((ext_vector_type(8)));
typedef float f32x4 __attribute__((ext_vector_type(4)));
typedef u16 u16x8 __attribute__((ext_vector_type(8)));
typedef u16 u16x4 __attribute__((ext_vector_type(4)));

#define B_ 16384

__device__ __forceinline__ u16 f2b(float f){
  unsigned u = __builtin_bit_cast(unsigned, f);
  u = (u + 0x7FFFu + ((u >> 16) & 1u)) >> 16;   // RNE
  return (u16)u;
}
__device__ __forceinline__ float b2f(u16 v){
  return __builtin_bit_cast(float, ((unsigned)v) << 16);
}
__device__ __forceinline__ void ld8(const u16* __restrict__ p, float* f){
  u16x8 v = *(const u16x8*)p;
  #pragma unroll
  for (int j = 0; j < 8; ++j) f[j] = b2f(v[j]);
}
__device__ __forceinline__ void st8(u16* __restrict__ p, const float* f){
  u16x8 v;
  #pragma unroll
  for (int j = 0; j < 8; ++j) v[j] = f2b(f[j]);
  *(u16x8*)p = v;
}

__device__ __forceinline__ void gload16(const u16* g, u16* lds){
  __builtin_amdgcn_global_load_lds(
      (const __attribute__((address_space(1))) unsigned int*)g,
      (__attribute__((address_space(3))) unsigned int*)lds, 16, 0, 0);
}

// ============== core256: 256x256 tile, BK=64, 8 waves (2M x 4N) =============
// Per-wave output 128x64 (acc[8][4]) -> LDS-read demand 77 B/cyc/CU, under the
// ~85 B/cyc b128 ceiling (the 64x64-wave kernels of R2-R5 were at 105 -> all
// capped ~25% MfmaUtil). LDS: ring-2 x (A[256][64]+B[256][64]) = 128 KiB,
// 1 block/CU, 8 waves. Rows 128B = 8 16B-slots, phys = s ^ (r&7) (R2-proven
// 0-conflict), staged via pre-swizzled global source + linear LDS dest.
// Schedule: stage tile t+1 (slot (t+1)&1, disjoint from live slot t&1 -> no
// race) at START of tile t; ~full tile of MFMA+ds_read cover before the
// boundary vmcnt(0)+barrier.
__device__ __forceinline__ void core256(const u16* __restrict__ A,
                                        const u16* __restrict__ Wt,
                                        int K, int m0, int n0, int nt,
                                        u16* sm, f32x4 acc[8][4])
{
  const int tid = threadIdx.x, lane = tid & 63;
  const int wm = (tid >> 8) * 128;
  const int wn = ((tid >> 6) & 3) * 64;

  #pragma unroll
  for (int m = 0; m < 8; ++m)
    #pragma unroll
    for (int n = 0; n < 4; ++n) acc[m][n] = (f32x4){0.f, 0.f, 0.f, 0.f};

  // staging: 8 gloads/tile, each = 512thr x 16B = 64 rows x 128B.
  const int srow  = tid >> 3;                 // row within 64-row slab
  const int sslot = (tid & 7) ^ (srow & 7);   // pre-swizzled source slot
  const u16* psrc[8];
  int pdst[8];
  const int wbase = (tid >> 6) * 512;         // u16
  #pragma unroll
  for (int g = 0; g < 4; ++g) {
    psrc[g]     = A  + (size_t)(m0 + g * 64 + srow) * K + sslot * 8;
    pdst[g]     = g * 4096 + wbase;
    psrc[g + 4] = Wt + (size_t)(n0 + g * 64 + srow) * K + sslot * 8;
    pdst[g + 4] = 16384 + g * 4096 + wbase;
  }

  // ds-read bases (u16): frag (m,kk) at abase[kk] + m*1024 (r&7 == lane&7)
  int abase[2], bbase[2];
  #pragma unroll
  for (int kk = 0; kk < 2; ++kk) {
    int phys = (kk * 4 + (lane >> 4)) ^ (lane & 7);
    abase[kk] = (wm + (lane & 15)) * 64 + phys * 8;
    bbase[kk] = 16384 + (wn + (lane & 15)) * 64 + phys * 8;
  }

  // prologue: stage tile 0 into slot 0
  #pragma unroll
  for (int g = 0; g < 8; ++g) gload16(psrc[g], sm + pdst[g]);
  asm volatile("s_waitcnt vmcnt(0)" ::: "memory");
  __builtin_amdgcn_s_barrier();

  for (int t = 0; t < nt; ++t) {
    if (t + 1 < nt) {                         // issue next tile FIRST
      u16* sl = sm + ((t + 1) & 1) * 32768;
      #pragma unroll
      for (int g = 0; g < 8; ++g) gload16(psrc[g] + (size_t)(t + 1) * 64, sl + pdst[g]);
    }
    const u16* s = sm + (t & 1) * 32768;
    #pragma unroll
    for (int kk = 0; kk < 2; ++kk) {
      bf16x8 bv[4];
      #pragma unroll
      for (int n = 0; n < 4; ++n) bv[n] = *(const bf16x8*)(s + bbase[kk] + n * 1024);
      #pragma unroll
      for (int mh = 0; mh < 2; ++mh) {
        bf16x8 av[4];
        #pragma unroll
        for (int m = 0; m < 4; ++m) av[m] = *(const bf16x8*)(s + abase[kk] + (mh * 4 + m) * 1024);
        __builtin_amdgcn_s_setprio(1);
        #pragma unroll
        for (int m = 0; m < 4; ++m)
          #pragma unroll
          for (int n = 0; n < 4; ++n)
            acc[mh*4+m][n] = __builtin_amdgcn_mfma_f32_16x16x32_bf16(av[m], bv[n], acc[mh*4+m][n], 0, 0, 0);
        __builtin_amdgcn_s_setprio(0);
      }
    }
    if (t + 1 < nt) {
      asm volatile("s_waitcnt vmcnt(0)" ::: "memory");
      __builtin_amdgcn_s_barrier();
    }
  }
}

// ---------------- stage kernels ----------------

// GEMM0: xb[16384,512] x Wt0[2816(pad),512]^T. grid 704 = 64 m x 11 n.
__global__ __launch_bounds__(512) void k_gemm0(const u16* __restrict__ xb,
    const u16* __restrict__ Wt0, const float* __restrict__ bias0,
    u16* __restrict__ E0, float* __restrict__ G0L)
{
  __shared__ __align__(16) u16 sm[65536];
  f32x4 acc[8][4];
  const int bid = blockIdx.x;                 // 704 = 8 * 88
  const int swz = (bid & 7) * 88 + (bid >> 3);
  const int m0 = (swz / 11) * 256, n0 = (swz % 11) * 256;
  core256(xb, Wt0, 512, m0, n0, 8, sm, acc);
  const int lane = threadIdx.x & 63;
  const int wm = (threadIdx.x >> 8) * 128, wn = ((threadIdx.x >> 6) & 3) * 64;
  #pragma unroll
  for (int mi = 0; mi < 8; ++mi)
    #pragma unroll
    for (int ni = 0; ni < 4; ++ni) {
      int gcol = n0 + wn + ni * 16 + (lane & 15);
      float bias = bias0[gcol];
      #pragma unroll
      for (int q = 0; q < 4; ++q) {
        int grow = m0 + wm + mi * 16 + ((lane >> 4) << 2) + q;
        float v = acc[mi][ni][q] + bias;
        if (gcol < 2560)      E0[(size_t)grow * 2560 + gcol] = f2b(fmaxf(v, 0.f));
        else if (gcol < 2586) G0L[(size_t)grow * 26 + (gcol - 2560)] = v;
      }
    }
}

// MIX0: 8 rows per block, vectorized (R5-proven)
__global__ __launch_bounds__(256) void k_mix0(const u16* __restrict__ E0,
    const float* __restrict__ G0L, u16* __restrict__ T1SH)
{
  const int b = blockIdx.x * 8 + (threadIdx.x >> 5);
  const int e0 = (threadIdx.x & 31) * 8;
  const float* gl = G0L + (size_t)b * 26;
  float g[4][4];
  #pragma unroll
  for (int t = 0; t < 4; ++t) {
    float l0 = gl[t*4+0], l1 = gl[t*4+1], l2 = gl[t*4+2], l3 = gl[t*4+3];
    float m = fmaxf(fmaxf(l0, l1), fmaxf(l2, l3));
    float e0e = expf(l0-m), e1 = expf(l1-m), e2 = expf(l2-m), e3 = expf(l3-m);
    float inv = 1.f / (e0e + e1 + e2 + e3);
    g[t][0] = e0e*inv; g[t][1] = e1*inv; g[t][2] = e2*inv; g[t][3] = e3*inv;
  }
  float gs[10];
  {
    float m = gl[16];
    #pragma unroll
    for (int j = 1; j < 10; ++j) m = fmaxf(m, gl[16 + j]);
    float s = 0.f;
    #pragma unroll
    for (int j = 0; j < 10; ++j) { gs[j] = expf(gl[16 + j] - m); s += gs[j]; }
    float inv = 1.f / s;
    #pragma unroll
    for (int j = 0; j < 10; ++j) gs[j] *= inv;
  }
  const u16* row = E0 + (size_t)b * 2560;
  float sh0[8], sh1[8], shacc[8];
  ld8(row + 2048 + e0, sh0);
  ld8(row + 2304 + e0, sh1);
  #pragma unroll
  for (int j = 0; j < 8; ++j) shacc[j] = gs[8]*sh0[j] + gs[9]*sh1[j];
  #pragma unroll
  for (int t = 0; t < 4; ++t) {
    float te0[8], te1[8], v[8];
    ld8(row + (t*2+0)*256 + e0, te0);
    ld8(row + (t*2+1)*256 + e0, te1);
    #pragma unroll
    for (int j = 0; j < 8; ++j) {
      v[j] = g[t][0]*te0[j] + g[t][1]*te1[j] + g[t][2]*sh0[j] + g[t][3]*sh1[j];
      shacc[j] += gs[t*2+0]*te0[j] + gs[t*2+1]*te1[j];
    }
    st8(T1SH + ((size_t)t * B_ + b) * 256 + e0, v);
  }
  st8(T1SH + ((size_t)4 * B_ + b) * 256 + e0, shacc);
}

// GATE1: 16 gate logits per row from t1, softmax -> G1S[16384][16] f32.
__global__ __launch_bounds__(256) void k_gate1(const u16* __restrict__ T1SH,
    const float* __restrict__ w_gate1, const float* __restrict__ b_gate1,
    float* __restrict__ G1S)
{
  const int lane = threadIdx.x & 63, wave = threadIdx.x >> 6;
  const int rbase = blockIdx.x * 64 + wave * 16;
  float w[16][4];
  #pragma unroll
  for (int zg = 0; zg < 16; ++zg) {
    int z = zg >> 2, gg = zg & 3;
    #pragma unroll
    for (int j = 0; j < 4; ++j)
      w[zg][j] = w_gate1[((size_t)z * 256 + lane * 4 + j) * 4 + gg];
  }
  for (int it = 0; it < 16; ++it) {
    int row = rbase + it;
    float lg[16];
    #pragma unroll
    for (int z = 0; z < 4; ++z) {
      u16x4 tv = *(const u16x4*)(T1SH + ((size_t)z * B_ + row) * 256 + lane * 4);
      float f0 = b2f(tv[0]), f1 = b2f(tv[1]), f2 = b2f(tv[2]), f3 = b2f(tv[3]);
      #pragma unroll
      for (int gg = 0; gg < 4; ++gg) {
        float p = f0*w[z*4+gg][0] + f1*w[z*4+gg][1] + f2*w[z*4+gg][2] + f3*w[z*4+gg][3];
        #pragma unroll
        for (int off = 1; off < 64; off <<= 1) p += __shfl_xor(p, off);
        lg[z*4+gg] = p + b_gate1[z*4+gg];
      }
    }
    float gt[16];
    #pragma unroll
    for (int z = 0; z < 4; ++z) {
      float l0=lg[z*4],l1=lg[z*4+1],l2=lg[z*4+2],l3=lg[z*4+3];
      float m = fmaxf(fmaxf(l0,l1),fmaxf(l2,l3));
      float e0=expf(l0-m),e1=expf(l1-m),e2=expf(l2-m),e3=expf(l3-m);
      float inv = 1.f/(e0+e1+e2+e3);
      gt[z*4]=e0*inv; gt[z*4+1]=e1*inv; gt[z*4+2]=e2*inv; gt[z*4+3]=e3*inv;
    }
    float* orow = G1S + (size_t)row * 16;
    #pragma unroll
    for (int gg = 0; gg < 16; ++gg) if (lane == gg) orow[gg] = gt[gg];
  }
}

// GEMM1: 10 panels: z<4 -> E1 cols 0..511 (2 panels each); z=4 -> SH1E.
__global__ __launch_bounds__(512) void k_gemm1(const u16* __restrict__ T1SH,
    const u16* __restrict__ Wt1, const float* __restrict__ bias1,
    u16* __restrict__ E1, u16* __restrict__ SH1E)
{
  __shared__ __align__(16) u16 sm[65536];
  f32x4 acc[8][4];
  const int bid = blockIdx.x;                 // 640 = 8 * 80
  const int swz = (bid & 7) * 80 + (bid >> 3);
  const int mi_ = swz / 10, pan = swz % 10;
  const int z  = (pan < 8) ? (pan >> 1) : 4;
  const int n0 = (pan < 8) ? (pan & 1) * 256 : (pan - 8) * 256;
  const int m0 = mi_ * 256;
  core256(T1SH + (size_t)z * B_ * 256, Wt1 + (size_t)z * 512 * 256, 256, m0, n0, 4, sm, acc);
  const int lane = threadIdx.x & 63;
  const int wm = (threadIdx.x >> 8) * 128, wn = ((threadIdx.x >> 6) & 3) * 64;
  const float* bias = bias1 + z * 512;
  #pragma unroll
  for (int mi = 0; mi < 8; ++mi)
    #pragma unroll
    for (int ni = 0; ni < 4; ++ni) {
      int gcol = n0 + wn + ni * 16 + (lane & 15);
      float bv = bias[gcol];
      #pragma unroll
      for (int q = 0; q < 4; ++q) {
        int grow = m0 + wm + mi * 16 + ((lane >> 4) << 2) + q;
        float v = fmaxf(acc[mi][ni][q] + bv, 0.f);
        if (z < 4) E1[((size_t)z * B_ + grow) * 512 + gcol] = f2b(v);
        else       SH1E[(size_t)grow * 512 + gcol] = f2b(v);
      }
    }
}

// MIX1: 8 rows per block, vectorized; gates from G1S.
__global__ __launch_bounds__(256) void k_mix1(const u16* __restrict__ E1,
    const float* __restrict__ G1S, const u16* __restrict__ SH1E, u16* __restrict__ T2)
{
  const int b = blockIdx.x * 8 + (threadIdx.x >> 5);
  const int e0 = (threadIdx.x & 31) * 8;
  float sh0[8], sh1[8];
  ld8(SH1E + (size_t)b * 512 + e0, sh0);
  ld8(SH1E + (size_t)b * 512 + 256 + e0, sh1);
  const float* gr = G1S + (size_t)b * 16;
  #pragma unroll
  for (int t = 0; t < 4; ++t) {
    float g0 = gr[t*4+0], g1 = gr[t*4+1], g2 = gr[t*4+2], g3 = gr[t*4+3];
    float te0[8], te1[8], v[8];
    ld8(E1 + ((size_t)t * B_ + b) * 512 + e0, te0);
    ld8(E1 + ((size_t)t * B_ + b) * 512 + 256 + e0, te1);
    #pragma unroll
    for (int j = 0; j < 8; ++j)
      v[j] = g0*te0[j] + g1*te1[j] + g2*sh0[j] + g3*sh1[j];
    st8(T2 + ((size_t)t * B_ + b) * 256 + e0, v);
  }
}

// ---------------- GEMM core v4 (R5-proven, kept for tower) ----------------
__device__ __forceinline__ void gemm_core4(const u16* __restrict__ A,
                                           const u16* __restrict__ Wt,
                                           int K, int m0, int n0, int nt,
                                           u16* sm, f32x4 acc[4][4])
{
  const int tid  = threadIdx.x;
  const int lane = tid & 63;
  const int wave = tid >> 6;
  const int wm   = ((tid >> 7) & 1) * 64;
  const int wn   = ((tid >> 6) & 1) * 64;

  f32x4 zero = {0.f, 0.f, 0.f, 0.f};
  #pragma unroll
  for (int mi = 0; mi < 4; ++mi)
    #pragma unroll
    for (int ni = 0; ni < 4; ++ni) acc[mi][ni] = zero;

  const int srow  = lane >> 3;
  const int gslot = (lane & 7) ^ srow;
  const u16* gsrc[8];
  int gdst[8];
  #pragma unroll
  for (int i = 0; i < 8; ++i) {
    int c = wave * 8 + i;
    if (c < 16) {
      gsrc[i] = A + (size_t)(m0 + c * 8 + srow) * K + gslot * 8;
      gdst[i] = c * 512;
    } else {
      gsrc[i] = Wt + (size_t)(n0 + (c - 16) * 8 + srow) * K + gslot * 8;
      gdst[i] = 8192 + (c - 16) * 512;
    }
  }

  int aoff[2][4], boff[2][4];
  #pragma unroll
  for (int kk = 0; kk < 2; ++kk) {
    #pragma unroll
    for (int m = 0; m < 4; ++m) {
      int r = wm + m * 16 + (lane & 15);
      aoff[kk][m] = r * 64 + (((kk * 4 + (lane >> 4)) ^ (r & 7)) * 8);
    }
    #pragma unroll
    for (int n = 0; n < 4; ++n) {
      int r = wn + n * 16 + (lane & 15);
      boff[kk][n] = 8192 + r * 64 + (((kk * 4 + (lane >> 4)) ^ (r & 7)) * 8);
    }
  }

  #pragma unroll
  for (int i = 0; i < 8; ++i) gload16(gsrc[i], sm + gdst[i]);
  asm volatile("s_waitcnt vmcnt(0)" ::: "memory");
  __builtin_amdgcn_s_barrier();

  for (int j = 0; j < nt; ++j) {
    if (j + 1 < nt) {
      u16* base = sm + ((j + 1) & 1) * 16384;
      #pragma unroll
      for (int i = 0; i < 8; ++i) gload16(gsrc[i] + (size_t)(j + 1) * 64, base + gdst[i]);
    }
    const u16* sa = sm + (j & 1) * 16384;
    #pragma unroll
    for (int kk = 0; kk < 2; ++kk) {
      bf16x8 av[4], bv[4];
      #pragma unroll
      for (int m = 0; m < 4; ++m) av[m] = *(const bf16x8*)(sa + aoff[kk][m]);
      #pragma unroll
      for (int n = 0; n < 4; ++n) bv[n] = *(const bf16x8*)(sa + boff[kk][n]);
      #pragma unroll
      for (int m = 0; m < 4; ++m)
        #pragma unroll
        for (int n = 0; n < 4; ++n)
          acc[m][n] = __builtin_amdgcn_mfma_f32_16x16x32_bf16(av[m], bv[n], acc[m][n], 0, 0, 0);
    }
    if (j + 1 < nt) {
      asm volatile("s_waitcnt vmcnt(0)" ::: "memory");
      __builtin_amdgcn_s_barrier();
    }
  }
}

// TOWER: h = relu(t2[z] x Wtw[z]^T + b_tw); logits; softmax2; clip.
__global__ __launch_bounds__(256) void k_tower(const u16* __restrict__ T2,
    const u16* __restrict__ Wtw, const float* __restrict__ b_tw,
    const float* __restrict__ w_out, const float* __restrict__ b_out,
    float* __restrict__ out)
{
  __shared__ __align__(16) u16 sm[32768];
  __shared__ float part[2][128][2];
  f32x4 acc[4][4];
  const int z = blockIdx.z;
  const int m0 = blockIdx.x * 128;
  gemm_core4(T2 + (size_t)z * B_ * 256, Wtw + (size_t)z * 128 * 256, 256, m0, 0, 4, sm, acc);
  const int lane = threadIdx.x & 63;
  const int wm = ((threadIdx.x >> 7) & 1) * 64, wn = ((threadIdx.x >> 6) & 1) * 64;
  #pragma unroll
  for (int mi = 0; mi < 4; ++mi) {
    #pragma unroll
    for (int r = 0; r < 4; ++r) {
      float p0 = 0.f, p1 = 0.f;
      #pragma unroll
      for (int ni = 0; ni < 4; ++ni) {
        int col = wn + ni * 16 + (lane & 15);
        float h = fmaxf(acc[mi][ni][r] + b_tw[z * 128 + col], 0.f);
        p0 += h * w_out[(z * 128 + col) * 2 + 0];
        p1 += h * w_out[(z * 128 + col) * 2 + 1];
      }
      #pragma unroll
      for (int off = 1; off < 16; off <<= 1) {
        p0 += __shfl_xor(p0, off);
        p1 += __shfl_xor(p1, off);
      }
      if ((lane & 15) == 0) {
        int rowl = wm + mi * 16 + ((lane >> 4) << 2) + r;
        part[wn >> 6][rowl][0] = p0;
        part[wn >> 6][rowl][1] = p1;
      }
    }
  }
  __syncthreads();
  if (threadIdx.x < 128) {
    int rowl = threadIdx.x;
    float l0 = part[0][rowl][0] + part[1][rowl][0] + b_out[z * 2 + 0];
    float l1 = part[0][rowl][1] + part[1][rowl][1] + b_out[z * 2 + 1];
    float mx = fmaxf(l0, l1);
    float e0 = expf(l0 - mx), e1 = expf(l1 - mx);
    float inv = 1.f / (e0 + e1);
    float p0 = fminf(fmaxf(e0 * inv, 1e-15f), 1.0f);
    float p1 = fminf(fmaxf(e1 * inv, 1e-15f), 1.0f);
    size_t o = ((size_t)z * B_ + m0 + rowl) * 2;
    out[o] = p0; out[o + 1] = p1;
  }
}

// PREP: cast x -> bf16; transposed bf16 weight panels (WT0 padded to 2816 rows,
// WT1 [5][512][256]) + bias vectors.
__global__ void k_prep(const float* __restrict__ x,
    const float* __restrict__ w_task0, const float* __restrict__ b_task0,
    const float* __restrict__ w_sh0,   const float* __restrict__ b_sh0,
    const float* __restrict__ w_gate0, const float* __restrict__ b_gate0,
    const float* __restrict__ w_gsh0,  const float* __restrict__ b_gsh0,
    const float* __restrict__ w_task1, const float* __restrict__ b_task1,
    const float* __restrict__ w_sh1,   const float* __restrict__ b_sh1,
    const float* __restrict__ w_tw,
    u16* __restrict__ xb, u16* __restrict__ Wt0, float* __restrict__ bias0,
    u16* __restrict__ Wt1, float* __restrict__ bias1, u16* __restrict__ Wtw)
{
  size_t i = (size_t)blockIdx.x * 256 + threadIdx.x;
  const size_t S_X8  = (size_t)16384 * 512 / 8; // 1048576
  const size_t S_WT0 = (size_t)2816 * 512;      // 1441792
  const size_t S_B0  = 2816;
  const size_t S_WT1 = (size_t)5 * 512 * 256;   // 655360
  const size_t S_B1  = 5 * 512;                 // 2560
  const size_t S_WTW = (size_t)4 * 128 * 256;   // 131072

  if (i < S_X8) {
    size_t o = i * 8;
    float4 a = *(const float4*)(x + o);
    float4 b = *(const float4*)(x + o + 4);
    u16x8 v;
    v[0] = f2b(a.x); v[1] = f2b(a.y); v[2] = f2b(a.z); v[3] = f2b(a.w);
    v[4] = f2b(b.x); v[5] = f2b(b.y); v[6] = f2b(b.z); v[7] = f2b(b.w);
    *(u16x8*)(xb + o) = v;
    return;
  }
  i -= S_X8;
  if (i < S_WT0) {
    int c = (int)(i / 512), f = (int)(i % 512);
    float v = 0.f;
    if (c < 2048)      { int te = c >> 8, o = c & 255; v = w_task0[((size_t)te * 512 + f) * 256 + o]; }
    else if (c < 2560) { int s = (c - 2048) >> 8, o = c & 255; v = w_sh0[((size_t)s * 512 + f) * 256 + o]; }
    else if (c < 2576) { int q = c - 2560; int t = q >> 2, gg = q & 3; v = w_gate0[((size_t)t * 512 + f) * 4 + gg]; }
    else if (c < 2586) { int j = c - 2576; v = w_gsh0[(size_t)f * 10 + j]; }
    Wt0[i] = f2b(v);
    return;
  }
  i -= S_WT0;
  if (i < S_B0) {
    int c = (int)i; float v = 0.f;
    if (c < 2048)      { int te = c >> 8, o = c & 255; v = b_task0[te * 256 + o]; }
    else if (c < 2560) { int s = (c - 2048) >> 8, o = c & 255; v = b_sh0[s * 256 + o]; }
    else if (c < 2576) { v = b_gate0[c - 2560]; }
    else if (c < 2586) { v = b_gsh0[c - 2576]; }
    bias0[c] = v;
    return;
  }
  i -= S_B0;
  if (i < S_WT1) {
    int z = (int)(i / (512 * 256)); int rem = (int)(i % (512 * 256));
    int c = rem / 256, f = rem % 256;
    float v;
    if (z < 4) { int ee = c >> 8, o = c & 255; v = w_task1[(((size_t)(z * 2 + ee)) * 256 + f) * 256 + o]; }
    else       { int s = c >> 8, o = c & 255; v = w_sh1[((size_t)s * 256 + f) * 256 + o]; }
    Wt1[i] = f2b(v);
    return;
  }
  i -= S_WT1;
  if (i < S_B1) {
    int z = (int)(i / 512); int c = (int)(i % 512);
    float v;
    if (z < 4) { int ee = c >> 8, o = c & 255; v = b_task1[(z * 2 + ee) * 256 + o]; }
    else       { int s = c >> 8, o = c & 255; v = b_sh1[s * 256 + o]; }
    bias1[(size_t)z * 512 + c] = v;
    return;
  }
  i -= S_B1;
  if (i < S_WTW) {
    int z = (int)(i / (128 * 256)); int rem = (int)(i % (128 * 256));
    int h = rem / 256, f = rem % 256;
    Wtw[i] = f2b(w_tw[((size_t)z * 256 + f) * 128 + h]);
    return;
  }
}

extern "C" void kernel_launch(void* const* d_in, const int* in_sizes, int n_in,
                              void* d_out, int out_size, void* d_ws, size_t ws_size,
                              hipStream_t stream)
{
  (void)in_sizes; (void)n_in; (void)out_size; (void)ws_size;
  const float* x       = (const float*)d_in[0];
  const float* w_task0 = (const float*)d_in[1];
  const float* b_task0 = (const float*)d_in[2];
  const float* w_sh0   = (const float*)d_in[3];
  const float* b_sh0   = (const float*)d_in[4];
  const float* w_gate0 = (const float*)d_in[5];
  const float* b_gate0 = (const float*)d_in[6];
  const float* w_gsh0  = (const float*)d_in[7];
  const float* b_gsh0  = (const float*)d_in[8];
  const float* w_task1 = (const float*)d_in[9];
  const float* b_task1 = (const float*)d_in[10];
  const float* w_sh1   = (const float*)d_in[11];
  const float* b_sh1   = (const float*)d_in[12];
  const float* w_gate1 = (const float*)d_in[13];
  const float* b_gate1 = (const float*)d_in[14];
  const float* w_tw    = (const float*)d_in[15];
  const float* b_tw    = (const float*)d_in[16];
  const float* w_out   = (const float*)d_in[17];
  const float* b_out   = (const float*)d_in[18];
  float* out = (float*)d_out;

  char* ws = (char*)d_ws;
  u16*   XB    = (u16*)  (ws + 0);            //  16,777,216  [16384][512] (dead after gemm0)
  u16*   SH1E  = (u16*)  (ws + 0);            //  16,777,216  reuses XB region
  u16*   WT0   = (u16*)  (ws + 16777216);     //   2,883,584  [2816][512]
  float* BIAS0 = (float*)(ws + 19660800);     //      11,264  [2816]
  u16*   WT1   = (u16*)  (ws + 19672064);     //   1,310,720  [5][512][256]
  float* BIAS1 = (float*)(ws + 20982784);     //      10,240  [5][512]
  u16*   WTW   = (u16*)  (ws + 20993024);     //     262,144  [4][128][256]
  u16*   E0    = (u16*)  (ws + 21255168);     //  83,886,080  [16384][2560] (T2 reuses)
  u16*   T2    = (u16*)  (ws + 21255168);     //  33,554,432  [4][16384][256]
  float* G0L   = (float*)(ws + 105141248);    //   1,703,936  [16384][26]
  u16*   T1SH  = (u16*)  (ws + 106845184);    //  41,943,040  [5][16384][256]
  u16*   E1    = (u16*)  (ws + 148788224);    //  67,108,864  [4][16384][512]
  float* G1S   = (float*)(ws + 215897088);    //   1,048,576  [16384][16]

  k_prep<<<12821, 256, 0, stream>>>(x, w_task0, b_task0, w_sh0, b_sh0, w_gate0, b_gate0,
      w_gsh0, b_gsh0, w_task1, b_task1, w_sh1, b_sh1, w_tw,
      XB, WT0, BIAS0, WT1, BIAS1, WTW);
  k_gemm0<<<704, 512, 0, stream>>>(XB, WT0, BIAS0, E0, G0L);
  k_mix0<<<2048, 256, 0, stream>>>(E0, G0L, T1SH);
  k_gate1<<<256, 256, 0, stream>>>(T1SH, w_gate1, b_gate1, G1S);
  k_gemm1<<<640, 512, 0, stream>>>(T1SH, WT1, BIAS1, E1, SH1E);
  k_mix1<<<2048, 256, 0, stream>>>(E1, G1S, SH1E, T2);
  k_tower<<<dim3(128, 1, 4), 256, 0, stream>>>(T2, WTW, b_tw, w_out, b_out, out);
}

// Round 8
// 193.561 us; speedup vs baseline: 2.3121x; 1.1526x over previous
//
#include <hip/hip_runtime.h>

typedef unsigned short u16;
typedef __bf16 bf16x8 __attribute__((ext_vector_type(8)));
typedef float f32x4 __attribute__((ext_vector_type(4)));
typedef u16 u16x8 __attribute__((ext_vector_type(8)));

#define B_ 16384

__device__ __forceinline__ u16 f2b(float f){
  unsigned u = __builtin_bit_cast(unsigned, f);
  u = (u + 0x7FFFu + ((u >> 16) & 1u)) >> 16;   // RNE
  return (u16)u;
}
__device__ __forceinline__ float b2f(u16 v){
  return __builtin_bit_cast(float, ((unsigned)v) << 16);
}
__device__ __forceinline__ void ld8(const u16* __restrict__ p, float* f){
  u16x8 v = *(const u16x8*)p;
  #pragma unroll
  for (int j = 0; j < 8; ++j) f[j] = b2f(v[j]);
}
__device__ __forceinline__ void st8(u16* __restrict__ p, const float* f){
  u16x8 v;
  #pragma unroll
  for (int j = 0; j < 8; ++j) v[j] = f2b(f[j]);
  *(u16x8*)p = v;
}

__device__ __forceinline__ void gload16(const u16* g, u16* lds){
  __builtin_amdgcn_global_load_lds(
      (const __attribute__((address_space(1))) unsigned int*)g,
      (__attribute__((address_space(3))) unsigned int*)lds, 16, 0, 0);
}

// ====== core256_8p: 256x256 tile, BK=64, 8 waves, 4-phase counted pipeline ==
// Geometry identical to R7 core256 (proven correct, 0 bank conflicts):
// 8 waves 2M x 4N, per-wave 128x64 (acc[8][4]); LDS 2 buf x (A[256][64] +
// B[256][64]) = 128 KiB; rows 128B/8 slots, phys = s ^ (r&7), pre-swizzled
// global source + linear LDS dest.
// NEW schedule (T3+T4+T5, guide's 8-phase/2-K-tiles template): per K-tile t,
// 4 phases (kk0|mh0, kk1|mh0, kk0|mh1, kk1|mh1). Each phase: ds_read regs ->
// stage 2 chunks of tile t+1 -> barrier -> lgkmcnt(0) -> setprio(1) + 16 MFMA
// + setprio(0) -> [counted vmcnt] -> barrier. B-frags (bv0/bv1) cached in
// regs across mh phases.
// Stage order for tile t+1: P1:{B0,B1} P2:{B2,B3} P3:{A0,A2} P4:{A1,A3}.
// Waits: end-P2 vmcnt(4) guarantees A1,A3(t) landed (P3/P4 read them);
//        end-P4 vmcnt(2) guarantees B(t+1)+A0,A2(t+1) landed (next P1/P2).
// Never drains to 0 in steady state. Every dependent ds_read is preceded by a
// memory-clobbered waitcnt asm -> no hoisting across the fence.
__device__ __forceinline__ void core256_8p(const u16* __restrict__ A,
                                           const u16* __restrict__ Wt,
                                           int K, int m0, int n0, int nt,
                                           u16* sm, f32x4 acc[8][4])
{
  const int tid = threadIdx.x, lane = tid & 63;
  const int wm = (tid >> 8) * 128;
  const int wn = ((tid >> 6) & 3) * 64;

  #pragma unroll
  for (int m = 0; m < 8; ++m)
    #pragma unroll
    for (int n = 0; n < 4; ++n) acc[m][n] = (f32x4){0.f, 0.f, 0.f, 0.f};

  const int srow  = tid >> 3;
  const int sslot = (tid & 7) ^ (srow & 7);
  const u16* psrc[8];
  int pdst[8];
  const int wbase = (tid >> 6) * 512;
  #pragma unroll
  for (int g = 0; g < 4; ++g) {
    psrc[g]     = A  + (size_t)(m0 + g * 64 + srow) * K + sslot * 8;   // A chunk g: rows g*64..+63
    pdst[g]     = g * 4096 + wbase;
    psrc[g + 4] = Wt + (size_t)(n0 + g * 64 + srow) * K + sslot * 8;   // B chunk g
    pdst[g + 4] = 16384 + g * 4096 + wbase;
  }

  int abase[2], bbase[2];
  #pragma unroll
  for (int kk = 0; kk < 2; ++kk) {
    int phys = (kk * 4 + (lane >> 4)) ^ (lane & 7);
    abase[kk] = (wm + (lane & 15)) * 64 + phys * 8;
    bbase[kk] = 16384 + (wn + (lane & 15)) * 64 + phys * 8;
  }

  // prologue: stage tile 0, age order B0 B1 B2 B3 A0 A2 A1 A3
  gload16(psrc[4], sm + pdst[4]); gload16(psrc[5], sm + pdst[5]);
  gload16(psrc[6], sm + pdst[6]); gload16(psrc[7], sm + pdst[7]);
  gload16(psrc[0], sm + pdst[0]); gload16(psrc[2], sm + pdst[2]);
  gload16(psrc[1], sm + pdst[1]); gload16(psrc[3], sm + pdst[3]);
  asm volatile("s_waitcnt vmcnt(2)" ::: "memory");   // A1,A3(0) may remain in flight
  __builtin_amdgcn_s_barrier();

  for (int t = 0; t < nt; ++t) {
    const u16* s = sm + (t & 1) * 32768;
    u16* d = sm + ((t + 1) & 1) * 32768;
    const bool nx = (t + 1 < nt);
    const size_t ko = (size_t)(t + 1) * 64;
    bf16x8 bv0[4], bv1[4], av[4];

    // ---- P1: (kk0, mh0) ----
    #pragma unroll
    for (int n = 0; n < 4; ++n) bv0[n] = *(const bf16x8*)(s + bbase[0] + n * 1024);
    #pragma unroll
    for (int m = 0; m < 4; ++m) av[m] = *(const bf16x8*)(s + abase[0] + m * 1024);
    if (nx) { gload16(psrc[4] + ko, d + pdst[4]); gload16(psrc[5] + ko, d + pdst[5]); }
    __builtin_amdgcn_s_barrier();
    asm volatile("s_waitcnt lgkmcnt(0)" ::: "memory");
    __builtin_amdgcn_s_setprio(1);
    #pragma unroll
    for (int m = 0; m < 4; ++m)
      #pragma unroll
      for (int n = 0; n < 4; ++n)
        acc[m][n] = __builtin_amdgcn_mfma_f32_16x16x32_bf16(av[m], bv0[n], acc[m][n], 0, 0, 0);
    __builtin_amdgcn_s_setprio(0);
    __builtin_amdgcn_s_barrier();

    // ---- P2: (kk1, mh0) ----
    #pragma unroll
    for (int n = 0; n < 4; ++n) bv1[n] = *(const bf16x8*)(s + bbase[1] + n * 1024);
    #pragma unroll
    for (int m = 0; m < 4; ++m) av[m] = *(const bf16x8*)(s + abase[1] + m * 1024);
    if (nx) { gload16(psrc[6] + ko, d + pdst[6]); gload16(psrc[7] + ko, d + pdst[7]); }
    __builtin_amdgcn_s_barrier();
    asm volatile("s_waitcnt lgkmcnt(0)" ::: "memory");
    __builtin_amdgcn_s_setprio(1);
    #pragma unroll
    for (int m = 0; m < 4; ++m)
      #pragma unroll
      for (int n = 0; n < 4; ++n)
        acc[m][n] = __builtin_amdgcn_mfma_f32_16x16x32_bf16(av[m], bv1[n], acc[m][n], 0, 0, 0);
    __builtin_amdgcn_s_setprio(0);
    if (nx) asm volatile("s_waitcnt vmcnt(4)" ::: "memory");   // A1,A3(t) landed
    else    asm volatile("s_waitcnt vmcnt(0)" ::: "memory");
    __builtin_amdgcn_s_barrier();

    // ---- P3: (kk0, mh1) ----
    #pragma unroll
    for (int m = 0; m < 4; ++m) av[m] = *(const bf16x8*)(s + abase[0] + (4 + m) * 1024);
    if (nx) { gload16(psrc[0] + ko, d + pdst[0]); gload16(psrc[2] + ko, d + pdst[2]); }
    __builtin_amdgcn_s_barrier();
    asm volatile("s_waitcnt lgkmcnt(0)" ::: "memory");
    __builtin_amdgcn_s_setprio(1);
    #pragma unroll
    for (int m = 0; m < 4; ++m)
      #pragma unroll
      for (int n = 0; n < 4; ++n)
        acc[4 + m][n] = __builtin_amdgcn_mfma_f32_16x16x32_bf16(av[m], bv0[n], acc[4 + m][n], 0, 0, 0);
    __builtin_amdgcn_s_setprio(0);
    __builtin_amdgcn_s_barrier();

    // ---- P4: (kk1, mh1) ----
    #pragma unroll
    for (int m = 0; m < 4; ++m) av[m] = *(const bf16x8*)(s + abase[1] + (4 + m) * 1024);
    if (nx) { gload16(psrc[1] + ko, d + pdst[1]); gload16(psrc[3] + ko, d + pdst[3]); }
    __builtin_amdgcn_s_barrier();
    asm volatile("s_waitcnt lgkmcnt(0)" ::: "memory");
    __builtin_amdgcn_s_setprio(1);
    #pragma unroll
    for (int m = 0; m < 4; ++m)
      #pragma unroll
      for (int n = 0; n < 4; ++n)
        acc[4 + m][n] = __builtin_amdgcn_mfma_f32_16x16x32_bf16(av[m], bv1[n], acc[4 + m][n], 0, 0, 0);
    __builtin_amdgcn_s_setprio(0);
    if (nx) asm volatile("s_waitcnt vmcnt(2)" ::: "memory");   // B+A0,A2(t+1) landed
    __builtin_amdgcn_s_barrier();
  }
}

// ---------------- stage kernels ----------------

// GEMM0: xb[16384,512] x Wt0[2816(pad),512]^T. grid 704 = 64 m x 11 n.
__global__ __launch_bounds__(512) void k_gemm0(const u16* __restrict__ xb,
    const u16* __restrict__ Wt0, const float* __restrict__ bias0,
    u16* __restrict__ E0, float* __restrict__ G0L)
{
  __shared__ __align__(16) u16 sm[65536];
  f32x4 acc[8][4];
  const int bid = blockIdx.x;                 // 704 = 8 * 88
  const int swz = (bid & 7) * 88 + (bid >> 3);
  const int m0 = (swz / 11) * 256, n0 = (swz % 11) * 256;
  core256_8p(xb, Wt0, 512, m0, n0, 8, sm, acc);
  const int lane = threadIdx.x & 63;
  const int wm = (threadIdx.x >> 8) * 128, wn = ((threadIdx.x >> 6) & 3) * 64;
  #pragma unroll
  for (int mi = 0; mi < 8; ++mi)
    #pragma unroll
    for (int ni = 0; ni < 4; ++ni) {
      int gcol = n0 + wn + ni * 16 + (lane & 15);
      float bias = bias0[gcol];
      #pragma unroll
      for (int q = 0; q < 4; ++q) {
        int grow = m0 + wm + mi * 16 + ((lane >> 4) << 2) + q;
        float v = acc[mi][ni][q] + bias;
        if (gcol < 2560)      E0[(size_t)grow * 2560 + gcol] = f2b(fmaxf(v, 0.f));
        else if (gcol < 2586) G0L[(size_t)grow * 26 + (gcol - 2560)] = v;
      }
    }
}

// MIX0 + fused gate1: 8 rows/block, each row = one 32-lane half-wave.
// Computes t1/sh1 (as before) AND the 16 level-1 gate logits per row
// (dot over the row's 256 t1 elems, 32-lane shuffle reduce) -> softmax -> G1S.
__global__ __launch_bounds__(256) void k_mix0(const u16* __restrict__ E0,
    const float* __restrict__ G0L, const float* __restrict__ WG1T,
    const float* __restrict__ b_gate1, u16* __restrict__ T1SH,
    float* __restrict__ G1S)
{
  const int b = blockIdx.x * 8 + (threadIdx.x >> 5);
  const int e0 = (threadIdx.x & 31) * 8;
  const float* gl = G0L + (size_t)b * 26;
  float g[4][4];
  #pragma unroll
  for (int t = 0; t < 4; ++t) {
    float l0 = gl[t*4+0], l1 = gl[t*4+1], l2 = gl[t*4+2], l3 = gl[t*4+3];
    float m = fmaxf(fmaxf(l0, l1), fmaxf(l2, l3));
    float e0e = expf(l0-m), e1 = expf(l1-m), e2 = expf(l2-m), e3 = expf(l3-m);
    float inv = 1.f / (e0e + e1 + e2 + e3);
    g[t][0] = e0e*inv; g[t][1] = e1*inv; g[t][2] = e2*inv; g[t][3] = e3*inv;
  }
  float gs[10];
  {
    float m = gl[16];
    #pragma unroll
    for (int j = 1; j < 10; ++j) m = fmaxf(m, gl[16 + j]);
    float s = 0.f;
    #pragma unroll
    for (int j = 0; j < 10; ++j) { gs[j] = expf(gl[16 + j] - m); s += gs[j]; }
    float inv = 1.f / s;
    #pragma unroll
    for (int j = 0; j < 10; ++j) gs[j] *= inv;
  }
  const u16* row = E0 + (size_t)b * 2560;
  float sh0[8], sh1[8], shacc[8];
  ld8(row + 2048 + e0, sh0);
  ld8(row + 2304 + e0, sh1);
  #pragma unroll
  for (int j = 0; j < 8; ++j) shacc[j] = gs[8]*sh0[j] + gs[9]*sh1[j];
  float gp[16];
  #pragma unroll
  for (int t = 0; t < 4; ++t) {
    float te0[8], te1[8], v[8];
    ld8(row + (t*2+0)*256 + e0, te0);
    ld8(row + (t*2+1)*256 + e0, te1);
    #pragma unroll
    for (int j = 0; j < 8; ++j) {
      v[j] = g[t][0]*te0[j] + g[t][1]*te1[j] + g[t][2]*sh0[j] + g[t][3]*sh1[j];
      shacc[j] += gs[t*2+0]*te0[j] + gs[t*2+1]*te1[j];
    }
    st8(T1SH + ((size_t)t * B_ + b) * 256 + e0, v);
    #pragma unroll
    for (int gg = 0; gg < 4; ++gg) {
      const float* wv = WG1T + ((size_t)(t * 4 + gg) * 256 + e0);
      float s = 0.f;
      #pragma unroll
      for (int j = 0; j < 8; ++j) s += v[j] * wv[j];
      gp[t * 4 + gg] = s;
    }
  }
  st8(T1SH + ((size_t)4 * B_ + b) * 256 + e0, shacc);
  // reduce 16 logits over the row's 32 lanes
  #pragma unroll
  for (int i = 0; i < 16; ++i) {
    #pragma unroll
    for (int off = 1; off < 32; off <<= 1)
      gp[i] += __shfl_xor(gp[i], off, 32);
  }
  if ((threadIdx.x & 31) == 0) {
    float* orow = G1S + (size_t)b * 16;
    #pragma unroll
    for (int z = 0; z < 4; ++z) {
      float l0 = gp[z*4+0] + b_gate1[z*4+0];
      float l1 = gp[z*4+1] + b_gate1[z*4+1];
      float l2 = gp[z*4+2] + b_gate1[z*4+2];
      float l3 = gp[z*4+3] + b_gate1[z*4+3];
      float m = fmaxf(fmaxf(l0, l1), fmaxf(l2, l3));
      float x0 = expf(l0-m), x1 = expf(l1-m), x2 = expf(l2-m), x3 = expf(l3-m);
      float inv = 1.f / (x0 + x1 + x2 + x3);
      orow[z*4+0] = x0*inv; orow[z*4+1] = x1*inv;
      orow[z*4+2] = x2*inv; orow[z*4+3] = x3*inv;
    }
  }
}

// GEMM1: 10 panels: z<4 -> E1 cols 0..511 (2 panels each); z=4 -> SH1E.
__global__ __launch_bounds__(512) void k_gemm1(const u16* __restrict__ T1SH,
    const u16* __restrict__ Wt1, const float* __restrict__ bias1,
    u16* __restrict__ E1, u16* __restrict__ SH1E)
{
  __shared__ __align__(16) u16 sm[65536];
  f32x4 acc[8][4];
  const int bid = blockIdx.x;                 // 640 = 8 * 80
  const int swz = (bid & 7) * 80 + (bid >> 3);
  const int mi_ = swz / 10, pan = swz % 10;
  const int z  = (pan < 8) ? (pan >> 1) : 4;
  const int n0 = (pan < 8) ? (pan & 1) * 256 : (pan - 8) * 256;
  const int m0 = mi_ * 256;
  core256_8p(T1SH + (size_t)z * B_ * 256, Wt1 + (size_t)z * 512 * 256, 256, m0, n0, 4, sm, acc);
  const int lane = threadIdx.x & 63;
  const int wm = (threadIdx.x >> 8) * 128, wn = ((threadIdx.x >> 6) & 3) * 64;
  const float* bias = bias1 + z * 512;
  #pragma unroll
  for (int mi = 0; mi < 8; ++mi)
    #pragma unroll
    for (int ni = 0; ni < 4; ++ni) {
      int gcol = n0 + wn + ni * 16 + (lane & 15);
      float bv = bias[gcol];
      #pragma unroll
      for (int q = 0; q < 4; ++q) {
        int grow = m0 + wm + mi * 16 + ((lane >> 4) << 2) + q;
        float v = fmaxf(acc[mi][ni][q] + bv, 0.f);
        if (z < 4) E1[((size_t)z * B_ + grow) * 512 + gcol] = f2b(v);
        else       SH1E[(size_t)grow * 512 + gcol] = f2b(v);
      }
    }
}

// MIX1: 8 rows per block, vectorized; gates from G1S.
__global__ __launch_bounds__(256) void k_mix1(const u16* __restrict__ E1,
    const float* __restrict__ G1S, const u16* __restrict__ SH1E, u16* __restrict__ T2)
{
  const int b = blockIdx.x * 8 + (threadIdx.x >> 5);
  const int e0 = (threadIdx.x & 31) * 8;
  float sh0[8], sh1[8];
  ld8(SH1E + (size_t)b * 512 + e0, sh0);
  ld8(SH1E + (size_t)b * 512 + 256 + e0, sh1);
  const float* gr = G1S + (size_t)b * 16;
  #pragma unroll
  for (int t = 0; t < 4; ++t) {
    float g0 = gr[t*4+0], g1 = gr[t*4+1], g2 = gr[t*4+2], g3 = gr[t*4+3];
    float te0[8], te1[8], v[8];
    ld8(E1 + ((size_t)t * B_ + b) * 512 + e0, te0);
    ld8(E1 + ((size_t)t * B_ + b) * 512 + 256 + e0, te1);
    #pragma unroll
    for (int j = 0; j < 8; ++j)
      v[j] = g0*te0[j] + g1*te1[j] + g2*sh0[j] + g3*sh1[j];
    st8(T2 + ((size_t)t * B_ + b) * 256 + e0, v);
  }
}

// ---------------- GEMM core v4 (R5-proven, kept for tower) ----------------
__device__ __forceinline__ void gemm_core4(const u16* __restrict__ A,
                                           const u16* __restrict__ Wt,
                                           int K, int m0, int n0, int nt,
                                           u16* sm, f32x4 acc[4][4])
{
  const int tid  = threadIdx.x;
  const int lane = tid & 63;
  const int wave = tid >> 6;
  const int wm   = ((tid >> 7) & 1) * 64;
  const int wn   = ((tid >> 6) & 1) * 64;

  f32x4 zero = {0.f, 0.f, 0.f, 0.f};
  #pragma unroll
  for (int mi = 0; mi < 4; ++mi)
    #pragma unroll
    for (int ni = 0; ni < 4; ++ni) acc[mi][ni] = zero;

  const int srow  = lane >> 3;
  const int gslot = (lane & 7) ^ srow;
  const u16* gsrc[8];
  int gdst[8];
  #pragma unroll
  for (int i = 0; i < 8; ++i) {
    int c = wave * 8 + i;
    if (c < 16) {
      gsrc[i] = A + (size_t)(m0 + c * 8 + srow) * K + gslot * 8;
      gdst[i] = c * 512;
    } else {
      gsrc[i] = Wt + (size_t)(n0 + (c - 16) * 8 + srow) * K + gslot * 8;
      gdst[i] = 8192 + (c - 16) * 512;
    }
  }

  int aoff[2][4], boff[2][4];
  #pragma unroll
  for (int kk = 0; kk < 2; ++kk) {
    #pragma unroll
    for (int m = 0; m < 4; ++m) {
      int r = wm + m * 16 + (lane & 15);
      aoff[kk][m] = r * 64 + (((kk * 4 + (lane >> 4)) ^ (r & 7)) * 8);
    }
    #pragma unroll
    for (int n = 0; n < 4; ++n) {
      int r = wn + n * 16 + (lane & 15);
      boff[kk][n] = 8192 + r * 64 + (((kk * 4 + (lane >> 4)) ^ (r & 7)) * 8);
    }
  }

  #pragma unroll
  for (int i = 0; i < 8; ++i) gload16(gsrc[i], sm + gdst[i]);
  asm volatile("s_waitcnt vmcnt(0)" ::: "memory");
  __builtin_amdgcn_s_barrier();

  for (int j = 0; j < nt; ++j) {
    if (j + 1 < nt) {
      u16* base = sm + ((j + 1) & 1) * 16384;
      #pragma unroll
      for (int i = 0; i < 8; ++i) gload16(gsrc[i] + (size_t)(j + 1) * 64, base + gdst[i]);
    }
    const u16* sa = sm + (j & 1) * 16384;
    #pragma unroll
    for (int kk = 0; kk < 2; ++kk) {
      bf16x8 av[4], bv[4];
      #pragma unroll
      for (int m = 0; m < 4; ++m) av[m] = *(const bf16x8*)(sa + aoff[kk][m]);
      #pragma unroll
      for (int n = 0; n < 4; ++n) bv[n] = *(const bf16x8*)(sa + boff[kk][n]);
      #pragma unroll
      for (int m = 0; m < 4; ++m)
        #pragma unroll
        for (int n = 0; n < 4; ++n)
          acc[m][n] = __builtin_amdgcn_mfma_f32_16x16x32_bf16(av[m], bv[n], acc[m][n], 0, 0, 0);
    }
    if (j + 1 < nt) {
      asm volatile("s_waitcnt vmcnt(0)" ::: "memory");
      __builtin_amdgcn_s_barrier();
    }
  }
}

// TOWER: h = relu(t2[z] x Wtw[z]^T + b_tw); logits; softmax2; clip.
__global__ __launch_bounds__(256) void k_tower(const u16* __restrict__ T2,
    const u16* __restrict__ Wtw, const float* __restrict__ b_tw,
    const float* __restrict__ w_out, const float* __restrict__ b_out,
    float* __restrict__ out)
{
  __shared__ __align__(16) u16 sm[32768];
  __shared__ float part[2][128][2];
  f32x4 acc[4][4];
  const int z = blockIdx.z;
  const int m0 = blockIdx.x * 128;
  gemm_core4(T2 + (size_t)z * B_ * 256, Wtw + (size_t)z * 128 * 256, 256, m0, 0, 4, sm, acc);
  const int lane = threadIdx.x & 63;
  const int wm = ((threadIdx.x >> 7) & 1) * 64, wn = ((threadIdx.x >> 6) & 1) * 64;
  #pragma unroll
  for (int mi = 0; mi < 4; ++mi) {
    #pragma unroll
    for (int r = 0; r < 4; ++r) {
      float p0 = 0.f, p1 = 0.f;
      #pragma unroll
      for (int ni = 0; ni < 4; ++ni) {
        int col = wn + ni * 16 + (lane & 15);
        float h = fmaxf(acc[mi][ni][r] + b_tw[z * 128 + col], 0.f);
        p0 += h * w_out[(z * 128 + col) * 2 + 0];
        p1 += h * w_out[(z * 128 + col) * 2 + 1];
      }
      #pragma unroll
      for (int off = 1; off < 16; off <<= 1) {
        p0 += __shfl_xor(p0, off);
        p1 += __shfl_xor(p1, off);
      }
      if ((lane & 15) == 0) {
        int rowl = wm + mi * 16 + ((lane >> 4) << 2) + r;
        part[wn >> 6][rowl][0] = p0;
        part[wn >> 6][rowl][1] = p1;
      }
    }
  }
  __syncthreads();
  if (threadIdx.x < 128) {
    int rowl = threadIdx.x;
    float l0 = part[0][rowl][0] + part[1][rowl][0] + b_out[z * 2 + 0];
    float l1 = part[0][rowl][1] + part[1][rowl][1] + b_out[z * 2 + 1];
    float mx = fmaxf(l0, l1);
    float e0 = expf(l0 - mx), e1 = expf(l1 - mx);
    float inv = 1.f / (e0 + e1);
    float p0 = fminf(fmaxf(e0 * inv, 1e-15f), 1.0f);
    float p1 = fminf(fmaxf(e1 * inv, 1e-15f), 1.0f);
    size_t o = ((size_t)z * B_ + m0 + rowl) * 2;
    out[o] = p0; out[o + 1] = p1;
  }
}

// PREP: cast x -> bf16; transposed weight panels + biases + WG1T (gate1^T f32).
__global__ void k_prep(const float* __restrict__ x,
    const float* __restrict__ w_task0, const float* __restrict__ b_task0,
    const float* __restrict__ w_sh0,   const float* __restrict__ b_sh0,
    const float* __restrict__ w_gate0, const float* __restrict__ b_gate0,
    const float* __restrict__ w_gsh0,  const float* __restrict__ b_gsh0,
    const float* __restrict__ w_task1, const float* __restrict__ b_task1,
    const float* __restrict__ w_sh1,   const float* __restrict__ b_sh1,
    const float* __restrict__ w_gate1, const float* __restrict__ w_tw,
    u16* __restrict__ xb, u16* __restrict__ Wt0, float* __restrict__ bias0,
    u16* __restrict__ Wt1, float* __restrict__ bias1, u16* __restrict__ Wtw,
    float* __restrict__ WG1T)
{
  size_t i = (size_t)blockIdx.x * 256 + threadIdx.x;
  const size_t S_X8  = (size_t)16384 * 512 / 8; // 1048576
  const size_t S_WT0 = (size_t)2816 * 512;      // 1441792
  const size_t S_B0  = 2816;
  const size_t S_WT1 = (size_t)5 * 512 * 256;   // 655360
  const size_t S_B1  = 5 * 512;                 // 2560
  const size_t S_WTW = (size_t)4 * 128 * 256;   // 131072
  const size_t S_WG1 = 4096;

  if (i < S_X8) {
    size_t o = i * 8;
    float4 a = *(const float4*)(x + o);
    float4 b = *(const float4*)(x + o + 4);
    u16x8 v;
    v[0] = f2b(a.x); v[1] = f2b(a.y); v[2] = f2b(a.z); v[3] = f2b(a.w);
    v[4] = f2b(b.x); v[5] = f2b(b.y); v[6] = f2b(b.z); v[7] = f2b(b.w);
    *(u16x8*)(xb + o) = v;
    return;
  }
  i -= S_X8;
  if (i < S_WT0) {
    int c = (int)(i / 512), f = (int)(i % 512);
    float v = 0.f;
    if (c < 2048)      { int te = c >> 8, o = c & 255; v = w_task0[((size_t)te * 512 + f) * 256 + o]; }
    else if (c < 2560) { int s = (c - 2048) >> 8, o = c & 255; v = w_sh0[((size_t)s * 512 + f) * 256 + o]; }
    else if (c < 2576) { int q = c - 2560; int t = q >> 2, gg = q & 3; v = w_gate0[((size_t)t * 512 + f) * 4 + gg]; }
    else if (c < 2586) { int j = c - 2576; v = w_gsh0[(size_t)f * 10 + j]; }
    Wt0[i] = f2b(v);
    return;
  }
  i -= S_WT0;
  if (i < S_B0) {
    int c = (int)i; float v = 0.f;
    if (c < 2048)      { int te = c >> 8, o = c & 255; v = b_task0[te * 256 + o]; }
    else if (c < 2560) { int s = (c - 2048) >> 8, o = c & 255; v = b_sh0[s * 256 + o]; }
    else if (c < 2576) { v = b_gate0[c - 2560]; }
    else if (c < 2586) { v = b_gsh0[c - 2576]; }
    bias0[c] = v;
    return;
  }
  i -= S_B0;
  if (i < S_WT1) {
    int z = (int)(i / (512 * 256)); int rem = (int)(i % (512 * 256));
    int c = rem / 256, f = rem % 256;
    float v;
    if (z < 4) { int ee = c >> 8, o = c & 255; v = w_task1[(((size_t)(z * 2 + ee)) * 256 + f) * 256 + o]; }
    else       { int s = c >> 8, o = c & 255; v = w_sh1[((size_t)s * 256 + f) * 256 + o]; }
    Wt1[i] = f2b(v);
    return;
  }
  i -= S_WT1;
  if (i < S_B1) {
    int z = (int)(i / 512); int c = (int)(i % 512);
    float v;
    if (z < 4) { int ee = c >> 8, o = c & 255; v = b_task1[(z * 2 + ee) * 256 + o]; }
    else       { int s = c >> 8, o = c & 255; v = b_sh1[s * 256 + o]; }
    bias1[(size_t)z * 512 + c] = v;
    return;
  }
  i -= S_B1;
  if (i < S_WTW) {
    int z = (int)(i / (128 * 256)); int rem = (int)(i % (128 * 256));
    int h = rem / 256, f = rem % 256;
    Wtw[i] = f2b(w_tw[((size_t)z * 256 + f) * 128 + h]);
    return;
  }
  i -= S_WTW;
  if (i < S_WG1) {
    int t = (int)(i >> 10), gg = (int)((i >> 8) & 3), e = (int)(i & 255);
    WG1T[i] = w_gate1[((size_t)t * 256 + e) * 4 + gg];
    return;
  }
}

extern "C" void kernel_launch(void* const* d_in, const int* in_sizes, int n_in,
                              void* d_out, int out_size, void* d_ws, size_t ws_size,
                              hipStream_t stream)
{
  (void)in_sizes; (void)n_in; (void)out_size; (void)ws_size;
  const float* x       = (const float*)d_in[0];
  const float* w_task0 = (const float*)d_in[1];
  const float* b_task0 = (const float*)d_in[2];
  const float* w_sh0   = (const float*)d_in[3];
  const float* b_sh0   = (const float*)d_in[4];
  const float* w_gate0 = (const float*)d_in[5];
  const float* b_gate0 = (const float*)d_in[6];
  const float* w_gsh0  = (const float*)d_in[7];
  const float* b_gsh0  = (const float*)d_in[8];
  const float* w_task1 = (const float*)d_in[9];
  const float* b_task1 = (const float*)d_in[10];
  const float* w_sh1   = (const float*)d_in[11];
  const float* b_sh1   = (const float*)d_in[12];
  const float* w_gate1 = (const float*)d_in[13];
  const float* b_gate1 = (const float*)d_in[14];
  const float* w_tw    = (const float*)d_in[15];
  const float* b_tw    = (const float*)d_in[16];
  const float* w_out   = (const float*)d_in[17];
  const float* b_out   = (const float*)d_in[18];
  float* out = (float*)d_out;

  char* ws = (char*)d_ws;
  u16*   XB    = (u16*)  (ws + 0);            //  16,777,216  [16384][512] (dead after gemm0)
  u16*   SH1E  = (u16*)  (ws + 0);            //  16,777,216  reuses XB region
  u16*   WT0   = (u16*)  (ws + 16777216);     //   2,883,584  [2816][512]
  float* BIAS0 = (float*)(ws + 19660800);     //      11,264  [2816]
  u16*   WT1   = (u16*)  (ws + 19672064);     //   1,310,720  [5][512][256]
  float* BIAS1 = (float*)(ws + 20982784);     //      10,240  [5][512]
  u16*   WTW   = (u16*)  (ws + 20993024);     //     262,144  [4][128][256]
  u16*   E0    = (u16*)  (ws + 21255168);     //  83,886,080  [16384][2560] (T2 reuses)
  u16*   T2    = (u16*)  (ws + 21255168);     //  33,554,432  [4][16384][256]
  float* G0L   = (float*)(ws + 105141248);    //   1,703,936  [16384][26]
  u16*   T1SH  = (u16*)  (ws + 106845184);    //  41,943,040  [5][16384][256]
  u16*   E1    = (u16*)  (ws + 148788224);    //  67,108,864  [4][16384][512]
  float* G1S   = (float*)(ws + 215897088);    //   1,048,576  [16384][16]
  float* WG1T  = (float*)(ws + 216945664);    //      16,384  [4][4][256]

  k_prep<<<12837, 256, 0, stream>>>(x, w_task0, b_task0, w_sh0, b_sh0, w_gate0, b_gate0,
      w_gsh0, b_gsh0, w_task1, b_task1, w_sh1, b_sh1, w_gate1, w_tw,
      XB, WT0, BIAS0, WT1, BIAS1, WTW, WG1T);
  k_gemm0<<<704, 512, 0, stream>>>(XB, WT0, BIAS0, E0, G0L);
  k_mix0<<<2048, 256, 0, stream>>>(E0, G0L, WG1T, b_gate1, T1SH, G1S);
  k_gemm1<<<640, 512, 0, stream>>>(T1SH, WT1, BIAS1, E1, SH1E);
  k_mix1<<<2048, 256, 0, stream>>>(E1, G1S, SH1E, T2);
  k_tower<<<dim3(128, 1, 4), 256, 0, stream>>>(T2, WTW, b_tw, w_out, b_out, out);
}

// Round 9
// 179.092 us; speedup vs baseline: 2.4989x; 1.0808x over previous
//
#include <hip/hip_runtime.h>

typedef unsigned short u16;
typedef __bf16 bf16x8 __attribute__((ext_vector_type(8)));
typedef float f32x4 __attribute__((ext_vector_type(4)));
typedef u16 u16x8 __attribute__((ext_vector_type(8)));

#define B_ 16384

__device__ __forceinline__ u16 f2b(float f){
  unsigned u = __builtin_bit_cast(unsigned, f);
  u = (u + 0x7FFFu + ((u >> 16) & 1u)) >> 16;   // RNE
  return (u16)u;
}
__device__ __forceinline__ float b2f(u16 v){
  return __builtin_bit_cast(float, ((unsigned)v) << 16);
}
__device__ __forceinline__ void ld8(const u16* __restrict__ p, float* f){
  u16x8 v = *(const u16x8*)p;
  #pragma unroll
  for (int j = 0; j < 8; ++j) f[j] = b2f(v[j]);
}
__device__ __forceinline__ void st8(u16* __restrict__ p, const float* f){
  u16x8 v;
  #pragma unroll
  for (int j = 0; j < 8; ++j) v[j] = f2b(f[j]);
  *(u16x8*)p = v;
}

__device__ __forceinline__ void gload16(const u16* g, u16* lds){
  __builtin_amdgcn_global_load_lds(
      (const __attribute__((address_space(1))) unsigned int*)g,
      (__attribute__((address_space(3))) unsigned int*)lds, 16, 0, 0);
}

// ===== core32: BM=256, BN=128, BK=32, ring-3, counted vmcnt, 2 blocks/CU ====
// R3's proven-best structure (62.8us) + NEW conflict-free row-pair layout.
// 512 thr = 8 waves (4M x 2N), per-wave 64x64 (acc[4][4] of 16x16x32).
// LDS slot = A 16KB + B 8KB = 24KB; ring-3 = 72KB -> 2 blocks/CU (the R3/R4
// lesson: cross-block TLP is the overlap engine).
// Layout: 128B lines hold row-pairs (2L,2L+1); logical slot s' = (r&1)*4 + k4
// (k4 = 16B K-group 0..3), phys = s' ^ (L&7). A wave b128 frag read touches
// 8 lines x 8 phys slots exactly once -> 0 bank conflicts (vs R3's 5.5M with
// the 4-slot XOR). Staged via pre-swizzled global source + linear LDS dest:
// source swizzle s' = (l&7)^((l>>3)&7) is chunk-independent.
// Schedule per K-step j: STAGE(j+2) -> ds_read frags -> 16 MFMA -> vmcnt(3)
// (stage(j+1) landed; never drain-0 in steady state) -> barrier.
__device__ __forceinline__ void core32(const u16* __restrict__ A,
                                       const u16* __restrict__ Wt,
                                       int K, int m0, int n0, int nt,
                                       u16* sm, f32x4 acc[4][4])
{
  const int tid = threadIdx.x, lane = tid & 63, wave = tid >> 6;
  const int wm = ((tid >> 7) & 3) * 64;
  const int wn = ((tid >> 6) & 1) * 64;

  #pragma unroll
  for (int m = 0; m < 4; ++m)
    #pragma unroll
    for (int n = 0; n < 4; ++n) acc[m][n] = (f32x4){0.f, 0.f, 0.f, 0.f};

  // ---- staging: 24 chunks of 1KB (A: 0..15 rows 16c.., B: 16..23), 3/wave
  const int s_    = (lane & 7) ^ ((lane >> 3) & 7);   // logical slot (involution)
  const int srow2 = 2 * (lane >> 3) + (s_ >> 2);      // row within 16-row chunk
  const int sk    = (s_ & 3) * 8;                     // k elem offset
  const u16* gsrc[3];
  int gdst[3];
  #pragma unroll
  for (int i = 0; i < 3; ++i) {
    int c = wave * 3 + i;
    if (c < 16) {
      gsrc[i] = A + (size_t)(m0 + c * 16 + srow2) * K + sk;
      gdst[i] = c * 512;
    } else {
      gsrc[i] = Wt + (size_t)(n0 + (c - 16) * 16 + srow2) * K + sk;
      gdst[i] = 8192 + (c - 16) * 512;
    }
  }

  // ---- ds-read offsets (u16): r -> line r>>1, s' = (r&1)*4 + (lane>>4)
  int aoff[4], boff[4];
  #pragma unroll
  for (int m = 0; m < 4; ++m) {
    int r = wm + m * 16 + (lane & 15);
    int L = r >> 1;
    int phys = (((r & 1) << 2) + (lane >> 4)) ^ (L & 7);
    aoff[m] = L * 64 + phys * 8;
  }
  #pragma unroll
  for (int n = 0; n < 4; ++n) {
    int r = wn + n * 16 + (lane & 15);
    int L = r >> 1;
    int phys = (((r & 1) << 2) + (lane >> 4)) ^ (L & 7);
    boff[n] = 8192 + L * 64 + phys * 8;
  }

  // prologue: stage steps 0,1 into slots 0,1
  #pragma unroll
  for (int j = 0; j < 2; ++j) {
    u16* sl = sm + j * 12288;
    #pragma unroll
    for (int i = 0; i < 3; ++i) gload16(gsrc[i] + j * 32, sl + gdst[i]);
  }
  asm volatile("s_waitcnt vmcnt(3)" ::: "memory");   // step 0 landed
  __builtin_amdgcn_s_barrier();

  int cs = 0;
  for (int j = 0; j < nt; ++j) {
    if (j + 2 < nt) {                       // stage j+2 into slot of step j-1
      int ns = cs + 2; ns = (ns >= 3) ? ns - 3 : ns;
      u16* sl = sm + ns * 12288;
      #pragma unroll
      for (int i = 0; i < 3; ++i) gload16(gsrc[i] + (size_t)(j + 2) * 32, sl + gdst[i]);
    }
    const u16* sa = sm + cs * 12288;
    bf16x8 av[4], bv[4];
    #pragma unroll
    for (int m = 0; m < 4; ++m) av[m] = *(const bf16x8*)(sa + aoff[m]);
    #pragma unroll
    for (int n = 0; n < 4; ++n) bv[n] = *(const bf16x8*)(sa + boff[n]);
    __builtin_amdgcn_s_setprio(1);
    #pragma unroll
    for (int m = 0; m < 4; ++m)
      #pragma unroll
      for (int n = 0; n < 4; ++n)
        acc[m][n] = __builtin_amdgcn_mfma_f32_16x16x32_bf16(av[m], bv[n], acc[m][n], 0, 0, 0);
    __builtin_amdgcn_s_setprio(0);
    if (j + 2 < nt)      asm volatile("s_waitcnt vmcnt(3)" ::: "memory");
    else if (j + 1 < nt) asm volatile("s_waitcnt vmcnt(0)" ::: "memory");
    __builtin_amdgcn_s_barrier();
    cs = (cs == 2) ? 0 : cs + 1;
  }
}

// ---------------- stage kernels ----------------

// GEMM0: xb[16384,512] x Wt0[.,512]^T. grid 1344 = 64 m x 21 n, XCD-swizzled.
__global__ __launch_bounds__(512) void k_gemm0(const u16* __restrict__ xb,
    const u16* __restrict__ Wt0, const float* __restrict__ bias0,
    u16* __restrict__ E0, float* __restrict__ G0L)
{
  __shared__ __align__(16) u16 sm[36864];
  f32x4 acc[4][4];
  const int bid = blockIdx.x;                 // 1344 = 8 * 168
  const int swz = (bid & 7) * 168 + (bid >> 3);
  const int m0 = (swz / 21) * 256, n0 = (swz % 21) * 128;
  core32(xb, Wt0, 512, m0, n0, 16, sm, acc);
  const int lane = threadIdx.x & 63;
  const int wm = ((threadIdx.x >> 7) & 3) * 64, wn = ((threadIdx.x >> 6) & 1) * 64;
  #pragma unroll
  for (int mi = 0; mi < 4; ++mi)
    #pragma unroll
    for (int ni = 0; ni < 4; ++ni) {
      int gcol = n0 + wn + ni * 16 + (lane & 15);
      float bias = bias0[gcol];
      #pragma unroll
      for (int q = 0; q < 4; ++q) {
        int grow = m0 + wm + mi * 16 + ((lane >> 4) << 2) + q;
        float v = acc[mi][ni][q] + bias;
        if (gcol < 2560)      E0[(size_t)grow * 2560 + gcol] = f2b(fmaxf(v, 0.f));
        else if (gcol < 2586) G0L[(size_t)grow * 26 + (gcol - 2560)] = v;
      }
    }
}

// MIX0 + fused gate1 (R8-proven): 8 rows/block, 32-lane half-wave per row.
__global__ __launch_bounds__(256) void k_mix0(const u16* __restrict__ E0,
    const float* __restrict__ G0L, const float* __restrict__ WG1T,
    const float* __restrict__ b_gate1, u16* __restrict__ T1SH,
    float* __restrict__ G1S)
{
  const int b = blockIdx.x * 8 + (threadIdx.x >> 5);
  const int e0 = (threadIdx.x & 31) * 8;
  const float* gl = G0L + (size_t)b * 26;
  float g[4][4];
  #pragma unroll
  for (int t = 0; t < 4; ++t) {
    float l0 = gl[t*4+0], l1 = gl[t*4+1], l2 = gl[t*4+2], l3 = gl[t*4+3];
    float m = fmaxf(fmaxf(l0, l1), fmaxf(l2, l3));
    float e0e = expf(l0-m), e1 = expf(l1-m), e2 = expf(l2-m), e3 = expf(l3-m);
    float inv = 1.f / (e0e + e1 + e2 + e3);
    g[t][0] = e0e*inv; g[t][1] = e1*inv; g[t][2] = e2*inv; g[t][3] = e3*inv;
  }
  float gs[10];
  {
    float m = gl[16];
    #pragma unroll
    for (int j = 1; j < 10; ++j) m = fmaxf(m, gl[16 + j]);
    float s = 0.f;
    #pragma unroll
    for (int j = 0; j < 10; ++j) { gs[j] = expf(gl[16 + j] - m); s += gs[j]; }
    float inv = 1.f / s;
    #pragma unroll
    for (int j = 0; j < 10; ++j) gs[j] *= inv;
  }
  const u16* row = E0 + (size_t)b * 2560;
  float sh0[8], sh1[8], shacc[8];
  ld8(row + 2048 + e0, sh0);
  ld8(row + 2304 + e0, sh1);
  #pragma unroll
  for (int j = 0; j < 8; ++j) shacc[j] = gs[8]*sh0[j] + gs[9]*sh1[j];
  float gp[16];
  #pragma unroll
  for (int t = 0; t < 4; ++t) {
    float te0[8], te1[8], v[8];
    ld8(row + (t*2+0)*256 + e0, te0);
    ld8(row + (t*2+1)*256 + e0, te1);
    #pragma unroll
    for (int j = 0; j < 8; ++j) {
      v[j] = g[t][0]*te0[j] + g[t][1]*te1[j] + g[t][2]*sh0[j] + g[t][3]*sh1[j];
      shacc[j] += gs[t*2+0]*te0[j] + gs[t*2+1]*te1[j];
    }
    st8(T1SH + ((size_t)t * B_ + b) * 256 + e0, v);
    #pragma unroll
    for (int gg = 0; gg < 4; ++gg) {
      const float* wv = WG1T + ((size_t)(t * 4 + gg) * 256 + e0);
      float s = 0.f;
      #pragma unroll
      for (int j = 0; j < 8; ++j) s += v[j] * wv[j];
      gp[t * 4 + gg] = s;
    }
  }
  st8(T1SH + ((size_t)4 * B_ + b) * 256 + e0, shacc);
  #pragma unroll
  for (int i = 0; i < 16; ++i) {
    #pragma unroll
    for (int off = 1; off < 32; off <<= 1)
      gp[i] += __shfl_xor(gp[i], off, 32);
  }
  if ((threadIdx.x & 31) == 0) {
    float* orow = G1S + (size_t)b * 16;
    #pragma unroll
    for (int z = 0; z < 4; ++z) {
      float l0 = gp[z*4+0] + b_gate1[z*4+0];
      float l1 = gp[z*4+1] + b_gate1[z*4+1];
      float l2 = gp[z*4+2] + b_gate1[z*4+2];
      float l3 = gp[z*4+3] + b_gate1[z*4+3];
      float m = fmaxf(fmaxf(l0, l1), fmaxf(l2, l3));
      float x0 = expf(l0-m), x1 = expf(l1-m), x2 = expf(l2-m), x3 = expf(l3-m);
      float inv = 1.f / (x0 + x1 + x2 + x3);
      orow[z*4+0] = x0*inv; orow[z*4+1] = x1*inv;
      orow[z*4+2] = x2*inv; orow[z*4+3] = x3*inv;
    }
  }
}

// GEMM1: 20 panels (z 0..4 x 4 n-tiles of 128) x 64 m-blocks, same core.
__global__ __launch_bounds__(512) void k_gemm1(const u16* __restrict__ T1SH,
    const u16* __restrict__ Wt1, const float* __restrict__ bias1,
    u16* __restrict__ E1, u16* __restrict__ SH1E)
{
  __shared__ __align__(16) u16 sm[36864];
  f32x4 acc[4][4];
  const int bid = blockIdx.x;                 // 1280 = 8 * 160
  const int swz = (bid & 7) * 160 + (bid >> 3);
  const int mi_ = swz / 20, pan = swz % 20;
  const int z  = pan >> 2;
  const int n0 = (pan & 3) * 128;
  const int m0 = mi_ * 256;
  core32(T1SH + (size_t)z * B_ * 256, Wt1 + (size_t)z * 512 * 256, 256, m0, n0, 8, sm, acc);
  const int lane = threadIdx.x & 63;
  const int wm = ((threadIdx.x >> 7) & 3) * 64, wn = ((threadIdx.x >> 6) & 1) * 64;
  const float* bias = bias1 + z * 512;
  #pragma unroll
  for (int mi = 0; mi < 4; ++mi)
    #pragma unroll
    for (int ni = 0; ni < 4; ++ni) {
      int gcol = n0 + wn + ni * 16 + (lane & 15);
      float bv = bias[gcol];
      #pragma unroll
      for (int q = 0; q < 4; ++q) {
        int grow = m0 + wm + mi * 16 + ((lane >> 4) << 2) + q;
        float v = fmaxf(acc[mi][ni][q] + bv, 0.f);
        if (z < 4) E1[((size_t)z * B_ + grow) * 512 + gcol] = f2b(v);
        else       SH1E[(size_t)grow * 512 + gcol] = f2b(v);
      }
    }
}

// MIX1: 8 rows per block, vectorized; gates from G1S.
__global__ __launch_bounds__(256) void k_mix1(const u16* __restrict__ E1,
    const float* __restrict__ G1S, const u16* __restrict__ SH1E, u16* __restrict__ T2)
{
  const int b = blockIdx.x * 8 + (threadIdx.x >> 5);
  const int e0 = (threadIdx.x & 31) * 8;
  float sh0[8], sh1[8];
  ld8(SH1E + (size_t)b * 512 + e0, sh0);
  ld8(SH1E + (size_t)b * 512 + 256 + e0, sh1);
  const float* gr = G1S + (size_t)b * 16;
  #pragma unroll
  for (int t = 0; t < 4; ++t) {
    float g0 = gr[t*4+0], g1 = gr[t*4+1], g2 = gr[t*4+2], g3 = gr[t*4+3];
    float te0[8], te1[8], v[8];
    ld8(E1 + ((size_t)t * B_ + b) * 512 + e0, te0);
    ld8(E1 + ((size_t)t * B_ + b) * 512 + 256 + e0, te1);
    #pragma unroll
    for (int j = 0; j < 8; ++j)
      v[j] = g0*te0[j] + g1*te1[j] + g2*sh0[j] + g3*sh1[j];
    st8(T2 + ((size_t)t * B_ + b) * 256 + e0, v);
  }
}

// ---------------- GEMM core v4 (R5-proven, kept for tower) ----------------
__device__ __forceinline__ void gemm_core4(const u16* __restrict__ A,
                                           const u16* __restrict__ Wt,
                                           int K, int m0, int n0, int nt,
                                           u16* sm, f32x4 acc[4][4])
{
  const int tid  = threadIdx.x;
  const int lane = tid & 63;
  const int wave = tid >> 6;
  const int wm   = ((tid >> 7) & 1) * 64;
  const int wn   = ((tid >> 6) & 1) * 64;

  f32x4 zero = {0.f, 0.f, 0.f, 0.f};
  #pragma unroll
  for (int mi = 0; mi < 4; ++mi)
    #pragma unroll
    for (int ni = 0; ni < 4; ++ni) acc[mi][ni] = zero;

  const int srow  = lane >> 3;
  const int gslot = (lane & 7) ^ srow;
  const u16* gsrc[8];
  int gdst[8];
  #pragma unroll
  for (int i = 0; i < 8; ++i) {
    int c = wave * 8 + i;
    if (c < 16) {
      gsrc[i] = A + (size_t)(m0 + c * 8 + srow) * K + gslot * 8;
      gdst[i] = c * 512;
    } else {
      gsrc[i] = Wt + (size_t)(n0 + (c - 16) * 8 + srow) * K + gslot * 8;
      gdst[i] = 8192 + (c - 16) * 512;
    }
  }

  int aoff[2][4], boff[2][4];
  #pragma unroll
  for (int kk = 0; kk < 2; ++kk) {
    #pragma unroll
    for (int m = 0; m < 4; ++m) {
      int r = wm + m * 16 + (lane & 15);
      aoff[kk][m] = r * 64 + (((kk * 4 + (lane >> 4)) ^ (r & 7)) * 8);
    }
    #pragma unroll
    for (int n = 0; n < 4; ++n) {
      int r = wn + n * 16 + (lane & 15);
      boff[kk][n] = 8192 + r * 64 + (((kk * 4 + (lane >> 4)) ^ (r & 7)) * 8);
    }
  }

  #pragma unroll
  for (int i = 0; i < 8; ++i) gload16(gsrc[i], sm + gdst[i]);
  asm volatile("s_waitcnt vmcnt(0)" ::: "memory");
  __builtin_amdgcn_s_barrier();

  for (int j = 0; j < nt; ++j) {
    if (j + 1 < nt) {
      u16* base = sm + ((j + 1) & 1) * 16384;
      #pragma unroll
      for (int i = 0; i < 8; ++i) gload16(gsrc[i] + (size_t)(j + 1) * 64, base + gdst[i]);
    }
    const u16* sa = sm + (j & 1) * 16384;
    #pragma unroll
    for (int kk = 0; kk < 2; ++kk) {
      bf16x8 av[4], bv[4];
      #pragma unroll
      for (int m = 0; m < 4; ++m) av[m] = *(const bf16x8*)(sa + aoff[kk][m]);
      #pragma unroll
      for (int n = 0; n < 4; ++n) bv[n] = *(const bf16x8*)(sa + boff[kk][n]);
      #pragma unroll
      for (int m = 0; m < 4; ++m)
        #pragma unroll
        for (int n = 0; n < 4; ++n)
          acc[m][n] = __builtin_amdgcn_mfma_f32_16x16x32_bf16(av[m], bv[n], acc[m][n], 0, 0, 0);
    }
    if (j + 1 < nt) {
      asm volatile("s_waitcnt vmcnt(0)" ::: "memory");
      __builtin_amdgcn_s_barrier();
    }
  }
}

// TOWER: h = relu(t2[z] x Wtw[z]^T + b_tw); logits; softmax2; clip.
__global__ __launch_bounds__(256) void k_tower(const u16* __restrict__ T2,
    const u16* __restrict__ Wtw, const float* __restrict__ b_tw,
    const float* __restrict__ w_out, const float* __restrict__ b_out,
    float* __restrict__ out)
{
  __shared__ __align__(16) u16 sm[32768];
  __shared__ float part[2][128][2];
  f32x4 acc[4][4];
  const int z = blockIdx.z;
  const int m0 = blockIdx.x * 128;
  gemm_core4(T2 + (size_t)z * B_ * 256, Wtw + (size_t)z * 128 * 256, 256, m0, 0, 4, sm, acc);
  const int lane = threadIdx.x & 63;
  const int wm = ((threadIdx.x >> 7) & 1) * 64, wn = ((threadIdx.x >> 6) & 1) * 64;
  #pragma unroll
  for (int mi = 0; mi < 4; ++mi) {
    #pragma unroll
    for (int r = 0; r < 4; ++r) {
      float p0 = 0.f, p1 = 0.f;
      #pragma unroll
      for (int ni = 0; ni < 4; ++ni) {
        int col = wn + ni * 16 + (lane & 15);
        float h = fmaxf(acc[mi][ni][r] + b_tw[z * 128 + col], 0.f);
        p0 += h * w_out[(z * 128 + col) * 2 + 0];
        p1 += h * w_out[(z * 128 + col) * 2 + 1];
      }
      #pragma unroll
      for (int off = 1; off < 16; off <<= 1) {
        p0 += __shfl_xor(p0, off);
        p1 += __shfl_xor(p1, off);
      }
      if ((lane & 15) == 0) {
        int rowl = wm + mi * 16 + ((lane >> 4) << 2) + r;
        part[wn >> 6][rowl][0] = p0;
        part[wn >> 6][rowl][1] = p1;
      }
    }
  }
  __syncthreads();
  if (threadIdx.x < 128) {
    int rowl = threadIdx.x;
    float l0 = part[0][rowl][0] + part[1][rowl][0] + b_out[z * 2 + 0];
    float l1 = part[0][rowl][1] + part[1][rowl][1] + b_out[z * 2 + 1];
    float mx = fmaxf(l0, l1);
    float e0 = expf(l0 - mx), e1 = expf(l1 - mx);
    float inv = 1.f / (e0 + e1);
    float p0 = fminf(fmaxf(e0 * inv, 1e-15f), 1.0f);
    float p1 = fminf(fmaxf(e1 * inv, 1e-15f), 1.0f);
    size_t o = ((size_t)z * B_ + m0 + rowl) * 2;
    out[o] = p0; out[o + 1] = p1;
  }
}

// PREP: cast x -> bf16; transposed weight panels + biases + WG1T (gate1^T f32).
__global__ void k_prep(const float* __restrict__ x,
    const float* __restrict__ w_task0, const float* __restrict__ b_task0,
    const float* __restrict__ w_sh0,   const float* __restrict__ b_sh0,
    const float* __restrict__ w_gate0, const float* __restrict__ b_gate0,
    const float* __restrict__ w_gsh0,  const float* __restrict__ b_gsh0,
    const float* __restrict__ w_task1, const float* __restrict__ b_task1,
    const float* __restrict__ w_sh1,   const float* __restrict__ b_sh1,
    const float* __restrict__ w_gate1, const float* __restrict__ w_tw,
    u16* __restrict__ xb, u16* __restrict__ Wt0, float* __restrict__ bias0,
    u16* __restrict__ Wt1, float* __restrict__ bias1, u16* __restrict__ Wtw,
    float* __restrict__ WG1T)
{
  size_t i = (size_t)blockIdx.x * 256 + threadIdx.x;
  const size_t S_X8  = (size_t)16384 * 512 / 8; // 1048576
  const size_t S_WT0 = (size_t)2816 * 512;      // 1441792
  const size_t S_B0  = 2816;
  const size_t S_WT1 = (size_t)5 * 512 * 256;   // 655360
  const size_t S_B1  = 5 * 512;                 // 2560
  const size_t S_WTW = (size_t)4 * 128 * 256;   // 131072
  const size_t S_WG1 = 4096;

  if (i < S_X8) {
    size_t o = i * 8;
    float4 a = *(const float4*)(x + o);
    float4 b = *(const float4*)(x + o + 4);
    u16x8 v;
    v[0] = f2b(a.x); v[1] = f2b(a.y); v[2] = f2b(a.z); v[3] = f2b(a.w);
    v[4] = f2b(b.x); v[5] = f2b(b.y); v[6] = f2b(b.z); v[7] = f2b(b.w);
    *(u16x8*)(xb + o) = v;
    return;
  }
  i -= S_X8;
  if (i < S_WT0) {
    int c = (int)(i / 512), f = (int)(i % 512);
    float v = 0.f;
    if (c < 2048)      { int te = c >> 8, o = c & 255; v = w_task0[((size_t)te * 512 + f) * 256 + o]; }
    else if (c < 2560) { int s = (c - 2048) >> 8, o = c & 255; v = w_sh0[((size_t)s * 512 + f) * 256 + o]; }
    else if (c < 2576) { int q = c - 2560; int t = q >> 2, gg = q & 3; v = w_gate0[((size_t)t * 512 + f) * 4 + gg]; }
    else if (c < 2586) { int j = c - 2576; v = w_gsh0[(size_t)f * 10 + j]; }
    Wt0[i] = f2b(v);
    return;
  }
  i -= S_WT0;
  if (i < S_B0) {
    int c = (int)i; float v = 0.f;
    if (c < 2048)      { int te = c >> 8, o = c & 255; v = b_task0[te * 256 + o]; }
    else if (c < 2560) { int s = (c - 2048) >> 8, o = c & 255; v = b_sh0[s * 256 + o]; }
    else if (c < 2576) { v = b_gate0[c - 2560]; }
    else if (c < 2586) { v = b_gsh0[c - 2576]; }
    bias0[c] = v;
    return;
  }
  i -= S_B0;
  if (i < S_WT1) {
    int z = (int)(i / (512 * 256)); int rem = (int)(i % (512 * 256));
    int c = rem / 256, f = rem % 256;
    float v;
    if (z < 4) { int ee = c >> 8, o = c & 255; v = w_task1[(((size_t)(z * 2 + ee)) * 256 + f) * 256 + o]; }
    else       { int s = c >> 8, o = c & 255; v = w_sh1[((size_t)s * 256 + f) * 256 + o]; }
    Wt1[i] = f2b(v);
    return;
  }
  i -= S_WT1;
  if (i < S_B1) {
    int z = (int)(i / 512); int c = (int)(i % 512);
    float v;
    if (z < 4) { int ee = c >> 8, o = c & 255; v = b_task1[(z * 2 + ee) * 256 + o]; }
    else       { int s = c >> 8, o = c & 255; v = b_sh1[s * 256 + o]; }
    bias1[(size_t)z * 512 + c] = v;
    return;
  }
  i -= S_B1;
  if (i < S_WTW) {
    int z = (int)(i / (128 * 256)); int rem = (int)(i % (128 * 256));
    int h = rem / 256, f = rem % 256;
    Wtw[i] = f2b(w_tw[((size_t)z * 256 + f) * 128 + h]);
    return;
  }
  i -= S_WTW;
  if (i < S_WG1) {
    int t = (int)(i >> 10), gg = (int)((i >> 8) & 3), e = (int)(i & 255);
    WG1T[i] = w_gate1[((size_t)t * 256 + e) * 4 + gg];
    return;
  }
}

extern "C" void kernel_launch(void* const* d_in, const int* in_sizes, int n_in,
                              void* d_out, int out_size, void* d_ws, size_t ws_size,
                              hipStream_t stream)
{
  (void)in_sizes; (void)n_in; (void)out_size; (void)ws_size;
  const float* x       = (const float*)d_in[0];
  const float* w_task0 = (const float*)d_in[1];
  const float* b_task0 = (const float*)d_in[2];
  const float* w_sh0   = (const float*)d_in[3];
  const float* b_sh0   = (const float*)d_in[4];
  const float* w_gate0 = (const float*)d_in[5];
  const float* b_gate0 = (const float*)d_in[6];
  const float* w_gsh0  = (const float*)d_in[7];
  const float* b_gsh0  = (const float*)d_in[8];
  const float* w_task1 = (const float*)d_in[9];
  const float* b_task1 = (const float*)d_in[10];
  const float* w_sh1   = (const float*)d_in[11];
  const float* b_sh1   = (const float*)d_in[12];
  const float* w_gate1 = (const float*)d_in[13];
  const float* b_gate1 = (const float*)d_in[14];
  const float* w_tw    = (const float*)d_in[15];
  const float* b_tw    = (const float*)d_in[16];
  const float* w_out   = (const float*)d_in[17];
  const float* b_out   = (const float*)d_in[18];
  float* out = (float*)d_out;

  char* ws = (char*)d_ws;
  u16*   XB    = (u16*)  (ws + 0);            //  16,777,216  [16384][512] (dead after gemm0)
  u16*   SH1E  = (u16*)  (ws + 0);            //  16,777,216  reuses XB region
  u16*   WT0   = (u16*)  (ws + 16777216);     //   2,883,584  [2816][512]
  float* BIAS0 = (float*)(ws + 19660800);     //      11,264  [2816]
  u16*   WT1   = (u16*)  (ws + 19672064);     //   1,310,720  [5][512][256]
  float* BIAS1 = (float*)(ws + 20982784);     //      10,240  [5][512]
  u16*   WTW   = (u16*)  (ws + 20993024);     //     262,144  [4][128][256]
  u16*   E0    = (u16*)  (ws + 21255168);     //  83,886,080  [16384][2560] (T2 reuses)
  u16*   T2    = (u16*)  (ws + 21255168);     //  33,554,432  [4][16384][256]
  float* G0L   = (float*)(ws + 105141248);    //   1,703,936  [16384][26]
  u16*   T1SH  = (u16*)  (ws + 106845184);    //  41,943,040  [5][16384][256]
  u16*   E1    = (u16*)  (ws + 148788224);    //  67,108,864  [4][16384][512]
  float* G1S   = (float*)(ws + 215897088);    //   1,048,576  [16384][16]
  float* WG1T  = (float*)(ws + 216945664);    //      16,384  [4][4][256]

  k_prep<<<12837, 256, 0, stream>>>(x, w_task0, b_task0, w_sh0, b_sh0, w_gate0, b_gate0,
      w_gsh0, b_gsh0, w_task1, b_task1, w_sh1, b_sh1, w_gate1, w_tw,
      XB, WT0, BIAS0, WT1, BIAS1, WTW, WG1T);
  k_gemm0<<<1344, 512, 0, stream>>>(XB, WT0, BIAS0, E0, G0L);
  k_mix0<<<2048, 256, 0, stream>>>(E0, G0L, WG1T, b_gate1, T1SH, G1S);
  k_gemm1<<<1280, 512, 0, stream>>>(T1SH, WT1, BIAS1, E1, SH1E);
  k_mix1<<<2048, 256, 0, stream>>>(E1, G1S, SH1E, T2);
  k_tower<<<dim3(128, 1, 4), 256, 0, stream>>>(T2, WTW, b_tw, w_out, b_out, out);
}

// Round 10
// 171.899 us; speedup vs baseline: 2.6035x; 1.0418x over previous
//
#include <hip/hip_runtime.h>

typedef unsigned short u16;
typedef __bf16 bf16x8 __attribute__((ext_vector_type(8)));
typedef float f32x4 __attribute__((ext_vector_type(4)));
typedef u16 u16x8 __attribute__((ext_vector_type(8)));

#define B_ 16384

__device__ __forceinline__ u16 f2b(float f){
  unsigned u = __builtin_bit_cast(unsigned, f);
  u = (u + 0x7FFFu + ((u >> 16) & 1u)) >> 16;   // RNE
  return (u16)u;
}
__device__ __forceinline__ float b2f(u16 v){
  return __builtin_bit_cast(float, ((unsigned)v) << 16);
}
__device__ __forceinline__ void ld8(const u16* __restrict__ p, float* f){
  u16x8 v = *(const u16x8*)p;
  #pragma unroll
  for (int j = 0; j < 8; ++j) f[j] = b2f(v[j]);
}
__device__ __forceinline__ void st8(u16* __restrict__ p, const float* f){
  u16x8 v;
  #pragma unroll
  for (int j = 0; j < 8; ++j) v[j] = f2b(f[j]);
  *(u16x8*)p = v;
}

__device__ __forceinline__ void gload16(const u16* g, u16* lds){
  __builtin_amdgcn_global_load_lds(
      (const __attribute__((address_space(1))) unsigned int*)g,
      (__attribute__((address_space(3))) unsigned int*)lds, 16, 0, 0);
}

// ===== core32 (R9-proven): BM=256, BN=128, BK=32, ring-3, counted vmcnt =====
// 0 bank conflicts (row-pair layout), 2 blocks/CU, 62.4us on gemm0.
__device__ __forceinline__ void core32(const u16* __restrict__ A,
                                       const u16* __restrict__ Wt,
                                       int K, int m0, int n0, int nt,
                                       u16* sm, f32x4 acc[4][4])
{
  const int tid = threadIdx.x, lane = tid & 63, wave = tid >> 6;
  const int wm = ((tid >> 7) & 3) * 64;
  const int wn = ((tid >> 6) & 1) * 64;

  #pragma unroll
  for (int m = 0; m < 4; ++m)
    #pragma unroll
    for (int n = 0; n < 4; ++n) acc[m][n] = (f32x4){0.f, 0.f, 0.f, 0.f};

  const int s_    = (lane & 7) ^ ((lane >> 3) & 7);
  const int srow2 = 2 * (lane >> 3) + (s_ >> 2);
  const int sk    = (s_ & 3) * 8;
  const u16* gsrc[3];
  int gdst[3];
  #pragma unroll
  for (int i = 0; i < 3; ++i) {
    int c = wave * 3 + i;
    if (c < 16) {
      gsrc[i] = A + (size_t)(m0 + c * 16 + srow2) * K + sk;
      gdst[i] = c * 512;
    } else {
      gsrc[i] = Wt + (size_t)(n0 + (c - 16) * 16 + srow2) * K + sk;
      gdst[i] = 8192 + (c - 16) * 512;
    }
  }

  int aoff[4], boff[4];
  #pragma unroll
  for (int m = 0; m < 4; ++m) {
    int r = wm + m * 16 + (lane & 15);
    int L = r >> 1;
    int phys = (((r & 1) << 2) + (lane >> 4)) ^ (L & 7);
    aoff[m] = L * 64 + phys * 8;
  }
  #pragma unroll
  for (int n = 0; n < 4; ++n) {
    int r = wn + n * 16 + (lane & 15);
    int L = r >> 1;
    int phys = (((r & 1) << 2) + (lane >> 4)) ^ (L & 7);
    boff[n] = 8192 + L * 64 + phys * 8;
  }

  #pragma unroll
  for (int j = 0; j < 2; ++j) {
    u16* sl = sm + j * 12288;
    #pragma unroll
    for (int i = 0; i < 3; ++i) gload16(gsrc[i] + j * 32, sl + gdst[i]);
  }
  asm volatile("s_waitcnt vmcnt(3)" ::: "memory");
  __builtin_amdgcn_s_barrier();

  int cs = 0;
  for (int j = 0; j < nt; ++j) {
    if (j + 2 < nt) {
      int ns = cs + 2; ns = (ns >= 3) ? ns - 3 : ns;
      u16* sl = sm + ns * 12288;
      #pragma unroll
      for (int i = 0; i < 3; ++i) gload16(gsrc[i] + (size_t)(j + 2) * 32, sl + gdst[i]);
    }
    const u16* sa = sm + cs * 12288;
    bf16x8 av[4], bv[4];
    #pragma unroll
    for (int m = 0; m < 4; ++m) av[m] = *(const bf16x8*)(sa + aoff[m]);
    #pragma unroll
    for (int n = 0; n < 4; ++n) bv[n] = *(const bf16x8*)(sa + boff[n]);
    __builtin_amdgcn_s_setprio(1);
    #pragma unroll
    for (int m = 0; m < 4; ++m)
      #pragma unroll
      for (int n = 0; n < 4; ++n)
        acc[m][n] = __builtin_amdgcn_mfma_f32_16x16x32_bf16(av[m], bv[n], acc[m][n], 0, 0, 0);
    __builtin_amdgcn_s_setprio(0);
    if (j + 2 < nt)      asm volatile("s_waitcnt vmcnt(3)" ::: "memory");
    else if (j + 1 < nt) asm volatile("s_waitcnt vmcnt(0)" ::: "memory");
    __builtin_amdgcn_s_barrier();
    cs = (cs == 2) ? 0 : cs + 1;
  }
}

// ---------------- stage kernels ----------------

// GEMM0: xb[16384,512] x Wt0[.,512]^T. grid 1344 = 64 m x 21 n, XCD-swizzled.
__global__ __launch_bounds__(512) void k_gemm0(const u16* __restrict__ xb,
    const u16* __restrict__ Wt0, const float* __restrict__ bias0,
    u16* __restrict__ E0, float* __restrict__ G0L)
{
  __shared__ __align__(16) u16 sm[36864];
  f32x4 acc[4][4];
  const int bid = blockIdx.x;                 // 1344 = 8 * 168
  const int swz = (bid & 7) * 168 + (bid >> 3);
  const int m0 = (swz / 21) * 256, n0 = (swz % 21) * 128;
  core32(xb, Wt0, 512, m0, n0, 16, sm, acc);
  const int lane = threadIdx.x & 63;
  const int wm = ((threadIdx.x >> 7) & 3) * 64, wn = ((threadIdx.x >> 6) & 1) * 64;
  #pragma unroll
  for (int mi = 0; mi < 4; ++mi)
    #pragma unroll
    for (int ni = 0; ni < 4; ++ni) {
      int gcol = n0 + wn + ni * 16 + (lane & 15);
      float bias = bias0[gcol];
      #pragma unroll
      for (int q = 0; q < 4; ++q) {
        int grow = m0 + wm + mi * 16 + ((lane >> 4) << 2) + q;
        float v = acc[mi][ni][q] + bias;
        if (gcol < 2560)      E0[(size_t)grow * 2560 + gcol] = f2b(fmaxf(v, 0.f));
        else if (gcol < 2586) G0L[(size_t)grow * 26 + (gcol - 2560)] = v;
      }
    }
}

// MIX0 + fused gate1 (R8-proven): 8 rows/block, 32-lane half-wave per row.
__global__ __launch_bounds__(256) void k_mix0(const u16* __restrict__ E0,
    const float* __restrict__ G0L, const float* __restrict__ WG1T,
    const float* __restrict__ b_gate1, u16* __restrict__ T1SH,
    float* __restrict__ G1S)
{
  const int b = blockIdx.x * 8 + (threadIdx.x >> 5);
  const int e0 = (threadIdx.x & 31) * 8;
  const float* gl = G0L + (size_t)b * 26;
  float g[4][4];
  #pragma unroll
  for (int t = 0; t < 4; ++t) {
    float l0 = gl[t*4+0], l1 = gl[t*4+1], l2 = gl[t*4+2], l3 = gl[t*4+3];
    float m = fmaxf(fmaxf(l0, l1), fmaxf(l2, l3));
    float e0e = expf(l0-m), e1 = expf(l1-m), e2 = expf(l2-m), e3 = expf(l3-m);
    float inv = 1.f / (e0e + e1 + e2 + e3);
    g[t][0] = e0e*inv; g[t][1] = e1*inv; g[t][2] = e2*inv; g[t][3] = e3*inv;
  }
  float gs[10];
  {
    float m = gl[16];
    #pragma unroll
    for (int j = 1; j < 10; ++j) m = fmaxf(m, gl[16 + j]);
    float s = 0.f;
    #pragma unroll
    for (int j = 0; j < 10; ++j) { gs[j] = expf(gl[16 + j] - m); s += gs[j]; }
    float inv = 1.f / s;
    #pragma unroll
    for (int j = 0; j < 10; ++j) gs[j] *= inv;
  }
  const u16* row = E0 + (size_t)b * 2560;
  float sh0[8], sh1[8], shacc[8];
  ld8(row + 2048 + e0, sh0);
  ld8(row + 2304 + e0, sh1);
  #pragma unroll
  for (int j = 0; j < 8; ++j) shacc[j] = gs[8]*sh0[j] + gs[9]*sh1[j];
  float gp[16];
  #pragma unroll
  for (int t = 0; t < 4; ++t) {
    float te0[8], te1[8], v[8];
    ld8(row + (t*2+0)*256 + e0, te0);
    ld8(row + (t*2+1)*256 + e0, te1);
    #pragma unroll
    for (int j = 0; j < 8; ++j) {
      v[j] = g[t][0]*te0[j] + g[t][1]*te1[j] + g[t][2]*sh0[j] + g[t][3]*sh1[j];
      shacc[j] += gs[t*2+0]*te0[j] + gs[t*2+1]*te1[j];
    }
    st8(T1SH + ((size_t)t * B_ + b) * 256 + e0, v);
    #pragma unroll
    for (int gg = 0; gg < 4; ++gg) {
      const float* wv = WG1T + ((size_t)(t * 4 + gg) * 256 + e0);
      float s = 0.f;
      #pragma unroll
      for (int j = 0; j < 8; ++j) s += v[j] * wv[j];
      gp[t * 4 + gg] = s;
    }
  }
  st8(T1SH + ((size_t)4 * B_ + b) * 256 + e0, shacc);
  #pragma unroll
  for (int i = 0; i < 16; ++i) {
    #pragma unroll
    for (int off = 1; off < 32; off <<= 1)
      gp[i] += __shfl_xor(gp[i], off, 32);
  }
  if ((threadIdx.x & 31) == 0) {
    float* orow = G1S + (size_t)b * 16;
    #pragma unroll
    for (int z = 0; z < 4; ++z) {
      float l0 = gp[z*4+0] + b_gate1[z*4+0];
      float l1 = gp[z*4+1] + b_gate1[z*4+1];
      float l2 = gp[z*4+2] + b_gate1[z*4+2];
      float l3 = gp[z*4+3] + b_gate1[z*4+3];
      float m = fmaxf(fmaxf(l0, l1), fmaxf(l2, l3));
      float x0 = expf(l0-m), x1 = expf(l1-m), x2 = expf(l2-m), x3 = expf(l3-m);
      float inv = 1.f / (x0 + x1 + x2 + x3);
      orow[z*4+0] = x0*inv; orow[z*4+1] = x1*inv;
      orow[z*4+2] = x2*inv; orow[z*4+3] = x3*inv;
    }
  }
}

// GEMM1: 20 panels (z 0..4 x 4 n-tiles of 128) x 64 m-blocks, same core.
__global__ __launch_bounds__(512) void k_gemm1(const u16* __restrict__ T1SH,
    const u16* __restrict__ Wt1, const float* __restrict__ bias1,
    u16* __restrict__ E1, u16* __restrict__ SH1E)
{
  __shared__ __align__(16) u16 sm[36864];
  f32x4 acc[4][4];
  const int bid = blockIdx.x;                 // 1280 = 8 * 160
  const int swz = (bid & 7) * 160 + (bid >> 3);
  const int mi_ = swz / 20, pan = swz % 20;
  const int z  = pan >> 2;
  const int n0 = (pan & 3) * 128;
  const int m0 = mi_ * 256;
  core32(T1SH + (size_t)z * B_ * 256, Wt1 + (size_t)z * 512 * 256, 256, m0, n0, 8, sm, acc);
  const int lane = threadIdx.x & 63;
  const int wm = ((threadIdx.x >> 7) & 3) * 64, wn = ((threadIdx.x >> 6) & 1) * 64;
  const float* bias = bias1 + z * 512;
  #pragma unroll
  for (int mi = 0; mi < 4; ++mi)
    #pragma unroll
    for (int ni = 0; ni < 4; ++ni) {
      int gcol = n0 + wn + ni * 16 + (lane & 15);
      float bv = bias[gcol];
      #pragma unroll
      for (int q = 0; q < 4; ++q) {
        int grow = m0 + wm + mi * 16 + ((lane >> 4) << 2) + q;
        float v = fmaxf(acc[mi][ni][q] + bv, 0.f);
        if (z < 4) E1[((size_t)z * B_ + grow) * 512 + gcol] = f2b(v);
        else       SH1E[(size_t)grow * 512 + gcol] = f2b(v);
      }
    }
}

// TOWER2 (mix1 fused): A-tile = t2[z] built during reg-staging from E1/SH1E/G1S.
// BM=128, K=256(e-dim), BK=64, nt=4, 256 thr = 4 waves (2M x 2N), LDS ring-2.
// A: reg-staged (load 4 bf16x8 slices + per-row float4 gates, mix f32, f2b,
//    ds_write_b128 to the SAME linear LDS image gload_lds would write —
//    source pre-swizzle gslot=(lane&7)^srow retained; ds_read side unchanged).
// B: global_load_lds (Wtw). Numerics identical to mix1+tower (v->f2b->MFMA).
// Each wave: 4 A-chunks + 4 B-chunks (mix work balanced across waves).
// Stage(t+1) issued before MFMA(t); disjoint buffer parity; __syncthreads
// drains lgkm+vmcnt -> race-free.
__global__ __launch_bounds__(256) void k_tower2(const u16* __restrict__ E1,
    const u16* __restrict__ SH1E, const float* __restrict__ G1S,
    const u16* __restrict__ Wtw, const float* __restrict__ b_tw,
    const float* __restrict__ w_out, const float* __restrict__ b_out,
    float* __restrict__ out)
{
  __shared__ __align__(16) u16 sm[32768];
  __shared__ float part[2][128][2];
  f32x4 acc[4][4];
  const int z = blockIdx.z;
  const int m0 = blockIdx.x * 128;
  const int tid = threadIdx.x, lane = tid & 63, wave = tid >> 6;
  const int wm = ((tid >> 7) & 1) * 64, wn = ((tid >> 6) & 1) * 64;

  #pragma unroll
  for (int mi = 0; mi < 4; ++mi)
    #pragma unroll
    for (int ni = 0; ni < 4; ++ni) acc[mi][ni] = (f32x4){0.f, 0.f, 0.f, 0.f};

  const int srow  = lane >> 3;
  const int gslot = (lane & 7) ^ srow;
  const int koff0 = gslot * 8;

  // per-chunk constants
  int growA[4], adst[4], bdst[4];
  const u16* bsrc[4];
  #pragma unroll
  for (int i = 0; i < 4; ++i) {
    int c = wave * 4 + i;
    growA[i] = m0 + c * 8 + srow;
    adst[i]  = c * 512;
    bsrc[i]  = Wtw + (size_t)z * 128 * 256 + (size_t)(c * 8 + srow) * 256 + koff0;
    bdst[i]  = 8192 + c * 512;
  }
  const u16* E1z = E1 + (size_t)z * B_ * 512;

  // ds-read offsets (identical to gemm_core4 layout)
  int aoff[2][4], boff[2][4];
  #pragma unroll
  for (int kk = 0; kk < 2; ++kk) {
    #pragma unroll
    for (int m = 0; m < 4; ++m) {
      int r = wm + m * 16 + (lane & 15);
      aoff[kk][m] = r * 64 + (((kk * 4 + (lane >> 4)) ^ (r & 7)) * 8);
    }
    #pragma unroll
    for (int n = 0; n < 4; ++n) {
      int r = wn + n * 16 + (lane & 15);
      boff[kk][n] = 8192 + r * 64 + (((kk * 4 + (lane >> 4)) ^ (r & 7)) * 8);
    }
  }

  #define STAGE_T(J, BUF) do {                                                 \
    u16* buf_ = (BUF);                                                         \
    _Pragma("unroll")                                                          \
    for (int i_ = 0; i_ < 4; ++i_) {                                           \
      size_t eoff_ = (size_t)growA[i_] * 512 + (J) * 64 + koff0;               \
      u16x8 ea_ = *(const u16x8*)(E1z + eoff_);                                \
      u16x8 eb_ = *(const u16x8*)(E1z + eoff_ + 256);                          \
      u16x8 sa_ = *(const u16x8*)(SH1E + eoff_);                               \
      u16x8 sb_ = *(const u16x8*)(SH1E + eoff_ + 256);                         \
      float4 g_ = *(const float4*)(G1S + (size_t)growA[i_] * 16 + z * 4);      \
      u16x8 o_;                                                                \
      _Pragma("unroll")                                                        \
      for (int jj_ = 0; jj_ < 8; ++jj_)                                        \
        o_[jj_] = f2b(g_.x * b2f(ea_[jj_]) + g_.y * b2f(eb_[jj_])              \
                    + g_.z * b2f(sa_[jj_]) + g_.w * b2f(sb_[jj_]));            \
      *(uint4*)(buf_ + adst[i_] + lane * 8) = __builtin_bit_cast(uint4, o_);   \
      gload16(bsrc[i_] + (J) * 64, buf_ + bdst[i_]);                           \
    }                                                                          \
  } while (0)

  STAGE_T(0, sm);
  __syncthreads();

  #pragma unroll
  for (int t = 0; t < 4; ++t) {
    if (t + 1 < 4) STAGE_T(t + 1, sm + ((t + 1) & 1) * 16384);
    const u16* sa = sm + (t & 1) * 16384;
    #pragma unroll
    for (int kk = 0; kk < 2; ++kk) {
      bf16x8 av[4], bv[4];
      #pragma unroll
      for (int m = 0; m < 4; ++m) av[m] = *(const bf16x8*)(sa + aoff[kk][m]);
      #pragma unroll
      for (int n = 0; n < 4; ++n) bv[n] = *(const bf16x8*)(sa + boff[kk][n]);
      #pragma unroll
      for (int m = 0; m < 4; ++m)
        #pragma unroll
        for (int n = 0; n < 4; ++n)
          acc[m][n] = __builtin_amdgcn_mfma_f32_16x16x32_bf16(av[m], bv[n], acc[m][n], 0, 0, 0);
    }
    if (t + 1 < 4) __syncthreads();
  }
  #undef STAGE_T

  #pragma unroll
  for (int mi = 0; mi < 4; ++mi) {
    #pragma unroll
    for (int r = 0; r < 4; ++r) {
      float p0 = 0.f, p1 = 0.f;
      #pragma unroll
      for (int ni = 0; ni < 4; ++ni) {
        int col = wn + ni * 16 + (lane & 15);
        float h = fmaxf(acc[mi][ni][r] + b_tw[z * 128 + col], 0.f);
        p0 += h * w_out[(z * 128 + col) * 2 + 0];
        p1 += h * w_out[(z * 128 + col) * 2 + 1];
      }
      #pragma unroll
      for (int off = 1; off < 16; off <<= 1) {
        p0 += __shfl_xor(p0, off);
        p1 += __shfl_xor(p1, off);
      }
      if ((lane & 15) == 0) {
        int rowl = wm + mi * 16 + ((lane >> 4) << 2) + r;
        part[wn >> 6][rowl][0] = p0;
        part[wn >> 6][rowl][1] = p1;
      }
    }
  }
  __syncthreads();
  if (threadIdx.x < 128) {
    int rowl = threadIdx.x;
    float l0 = part[0][rowl][0] + part[1][rowl][0] + b_out[z * 2 + 0];
    float l1 = part[0][rowl][1] + part[1][rowl][1] + b_out[z * 2 + 1];
    float mx = fmaxf(l0, l1);
    float e0 = expf(l0 - mx), e1 = expf(l1 - mx);
    float inv = 1.f / (e0 + e1);
    float p0 = fminf(fmaxf(e0 * inv, 1e-15f), 1.0f);
    float p1 = fminf(fmaxf(e1 * inv, 1e-15f), 1.0f);
    size_t o = ((size_t)z * B_ + m0 + rowl) * 2;
    out[o] = p0; out[o + 1] = p1;
  }
}

// PREP: cast x -> bf16; transposed weight panels + biases + WG1T (gate1^T f32).
__global__ void k_prep(const float* __restrict__ x,
    const float* __restrict__ w_task0, const float* __restrict__ b_task0,
    const float* __restrict__ w_sh0,   const float* __restrict__ b_sh0,
    const float* __restrict__ w_gate0, const float* __restrict__ b_gate0,
    const float* __restrict__ w_gsh0,  const float* __restrict__ b_gsh0,
    const float* __restrict__ w_task1, const float* __restrict__ b_task1,
    const float* __restrict__ w_sh1,   const float* __restrict__ b_sh1,
    const float* __restrict__ w_gate1, const float* __restrict__ w_tw,
    u16* __restrict__ xb, u16* __restrict__ Wt0, float* __restrict__ bias0,
    u16* __restrict__ Wt1, float* __restrict__ bias1, u16* __restrict__ Wtw,
    float* __restrict__ WG1T)
{
  size_t i = (size_t)blockIdx.x * 256 + threadIdx.x;
  const size_t S_X8  = (size_t)16384 * 512 / 8; // 1048576
  const size_t S_WT0 = (size_t)2816 * 512;      // 1441792
  const size_t S_B0  = 2816;
  const size_t S_WT1 = (size_t)5 * 512 * 256;   // 655360
  const size_t S_B1  = 5 * 512;                 // 2560
  const size_t S_WTW = (size_t)4 * 128 * 256;   // 131072
  const size_t S_WG1 = 4096;

  if (i < S_X8) {
    size_t o = i * 8;
    float4 a = *(const float4*)(x + o);
    float4 b = *(const float4*)(x + o + 4);
    u16x8 v;
    v[0] = f2b(a.x); v[1] = f2b(a.y); v[2] = f2b(a.z); v[3] = f2b(a.w);
    v[4] = f2b(b.x); v[5] = f2b(b.y); v[6] = f2b(b.z); v[7] = f2b(b.w);
    *(u16x8*)(xb + o) = v;
    return;
  }
  i -= S_X8;
  if (i < S_WT0) {
    int c = (int)(i / 512), f = (int)(i % 512);
    float v = 0.f;
    if (c < 2048)      { int te = c >> 8, o = c & 255; v = w_task0[((size_t)te * 512 + f) * 256 + o]; }
    else if (c < 2560) { int s = (c - 2048) >> 8, o = c & 255; v = w_sh0[((size_t)s * 512 + f) * 256 + o]; }
    else if (c < 2576) { int q = c - 2560; int t = q >> 2, gg = q & 3; v = w_gate0[((size_t)t * 512 + f) * 4 + gg]; }
    else if (c < 2586) { int j = c - 2576; v = w_gsh0[(size_t)f * 10 + j]; }
    Wt0[i] = f2b(v);
    return;
  }
  i -= S_WT0;
  if (i < S_B0) {
    int c = (int)i; float v = 0.f;
    if (c < 2048)      { int te = c >> 8, o = c & 255; v = b_task0[te * 256 + o]; }
    else if (c < 2560) { int s = (c - 2048) >> 8, o = c & 255; v = b_sh0[s * 256 + o]; }
    else if (c < 2576) { v = b_gate0[c - 2560]; }
    else if (c < 2586) { v = b_gsh0[c - 2576]; }
    bias0[c] = v;
    return;
  }
  i -= S_B0;
  if (i < S_WT1) {
    int z = (int)(i / (512 * 256)); int rem = (int)(i % (512 * 256));
    int c = rem / 256, f = rem % 256;
    float v;
    if (z < 4) { int ee = c >> 8, o = c & 255; v = w_task1[(((size_t)(z * 2 + ee)) * 256 + f) * 256 + o]; }
    else       { int s = c >> 8, o = c & 255; v = w_sh1[((size_t)s * 256 + f) * 256 + o]; }
    Wt1[i] = f2b(v);
    return;
  }
  i -= S_WT1;
  if (i < S_B1) {
    int z = (int)(i / 512); int c = (int)(i % 512);
    float v;
    if (z < 4) { int ee = c >> 8, o = c & 255; v = b_task1[(z * 2 + ee) * 256 + o]; }
    else       { int s = c >> 8, o = c & 255; v = b_sh1[s * 256 + o]; }
    bias1[(size_t)z * 512 + c] = v;
    return;
  }
  i -= S_B1;
  if (i < S_WTW) {
    int z = (int)(i / (128 * 256)); int rem = (int)(i % (128 * 256));
    int h = rem / 256, f = rem % 256;
    Wtw[i] = f2b(w_tw[((size_t)z * 256 + f) * 128 + h]);
    return;
  }
  i -= S_WTW;
  if (i < S_WG1) {
    int t = (int)(i >> 10), gg = (int)((i >> 8) & 3), e = (int)(i & 255);
    WG1T[i] = w_gate1[((size_t)t * 256 + e) * 4 + gg];
    return;
  }
}

extern "C" void kernel_launch(void* const* d_in, const int* in_sizes, int n_in,
                              void* d_out, int out_size, void* d_ws, size_t ws_size,
                              hipStream_t stream)
{
  (void)in_sizes; (void)n_in; (void)out_size; (void)ws_size;
  const float* x       = (const float*)d_in[0];
  const float* w_task0 = (const float*)d_in[1];
  const float* b_task0 = (const float*)d_in[2];
  const float* w_sh0   = (const float*)d_in[3];
  const float* b_sh0   = (const float*)d_in[4];
  const float* w_gate0 = (const float*)d_in[5];
  const float* b_gate0 = (const float*)d_in[6];
  const float* w_gsh0  = (const float*)d_in[7];
  const float* b_gsh0  = (const float*)d_in[8];
  const float* w_task1 = (const float*)d_in[9];
  const float* b_task1 = (const float*)d_in[10];
  const float* w_sh1   = (const float*)d_in[11];
  const float* b_sh1   = (const float*)d_in[12];
  const float* w_gate1 = (const float*)d_in[13];
  const float* b_gate1 = (const float*)d_in[14];
  const float* w_tw    = (const float*)d_in[15];
  const float* b_tw    = (const float*)d_in[16];
  const float* w_out   = (const float*)d_in[17];
  const float* b_out   = (const float*)d_in[18];
  float* out = (float*)d_out;

  char* ws = (char*)d_ws;
  u16*   XB    = (u16*)  (ws + 0);            //  16,777,216  [16384][512] (dead after gemm0)
  u16*   SH1E  = (u16*)  (ws + 0);            //  16,777,216  reuses XB region
  u16*   WT0   = (u16*)  (ws + 16777216);     //   2,883,584  [2816][512]
  float* BIAS0 = (float*)(ws + 19660800);     //      11,264  [2816]
  u16*   WT1   = (u16*)  (ws + 19672064);     //   1,310,720  [5][512][256]
  float* BIAS1 = (float*)(ws + 20982784);     //      10,240  [5][512]
  u16*   WTW   = (u16*)  (ws + 20993024);     //     262,144  [4][128][256]
  u16*   E0    = (u16*)  (ws + 21255168);     //  83,886,080  [16384][2560]
  float* G0L   = (float*)(ws + 105141248);    //   1,703,936  [16384][26]
  u16*   T1SH  = (u16*)  (ws + 106845184);    //  41,943,040  [5][16384][256]
  u16*   E1    = (u16*)  (ws + 148788224);    //  67,108,864  [4][16384][512]
  float* G1S   = (float*)(ws + 215897088);    //   1,048,576  [16384][16]
  float* WG1T  = (float*)(ws + 216945664);    //      16,384  [4][4][256]

  k_prep<<<12837, 256, 0, stream>>>(x, w_task0, b_task0, w_sh0, b_sh0, w_gate0, b_gate0,
      w_gsh0, b_gsh0, w_task1, b_task1, w_sh1, b_sh1, w_gate1, w_tw,
      XB, WT0, BIAS0, WT1, BIAS1, WTW, WG1T);
  k_gemm0<<<1344, 512, 0, stream>>>(XB, WT0, BIAS0, E0, G0L);
  k_mix0<<<2048, 256, 0, stream>>>(E0, G0L, WG1T, b_gate1, T1SH, G1S);
  k_gemm1<<<1280, 512, 0, stream>>>(T1SH, WT1, BIAS1, E1, SH1E);
  k_tower2<<<dim3(128, 1, 4), 256, 0, stream>>>(E1, SH1E, G1S, WTW, b_tw, w_out, b_out, out);
}